// Round 4
// baseline (419.024 us; speedup 1.0000x reference)
//
#include <hip/hip_runtime.h>
#include <stdint.h>

#define DEV __device__ __forceinline__

// ---------------------------------------------------------------- helpers
DEV float tanh_fast(float x) {
  x = fminf(15.f, fmaxf(-15.f, x));
  float e = __expf(2.f * x);
  return __fdividef(e - 1.f, e + 1.f);
}

DEV uint32_t rotl32(uint32_t x, int r) { return (x << r) | (x >> (32 - r)); }

// JAX Threefry-2x32 with key = (0, 42)  (jax.random.key(42))
DEV void threefry_0_42(uint32_t x0, uint32_t x1, uint32_t& o0, uint32_t& o1) {
  const uint32_t ks0 = 0u, ks1 = 42u, ks2 = 0x1BD11BDAu ^ 42u;
  x0 += ks0; x1 += ks1;
#define TFR(r) { x0 += x1; x1 = rotl32(x1, (r)); x1 ^= x0; }
  TFR(13) TFR(15) TFR(26) TFR(6)  x0 += ks1; x1 += ks2 + 1u;
  TFR(17) TFR(29) TFR(16) TFR(24) x0 += ks2; x1 += ks0 + 2u;
  TFR(13) TFR(15) TFR(26) TFR(6)  x0 += ks0; x1 += ks1 + 3u;
  TFR(17) TFR(29) TFR(16) TFR(24) x0 += ks1; x1 += ks2 + 4u;
  TFR(13) TFR(15) TFR(26) TFR(6)  x0 += ks2; x1 += ks0 + 5u;
#undef TFR
  o0 = x0; o1 = x1;
}

DEV float wredmax(float v) {
#pragma unroll
  for (int off = 32; off > 0; off >>= 1) v = fmaxf(v, __shfl_xor(v, off));
  return v;
}
DEV float wredsum(float v) {
#pragma unroll
  for (int off = 32; off > 0; off >>= 1) v += __shfl_xor(v, off);
  return v;
}

// 16 FMAs of the 4x4 micro tile
#define MICRO_FMA(a, b, acc)                                            \
  acc[0][0] = fmaf(a.x, b.x, acc[0][0]); acc[0][1] = fmaf(a.x, b.y, acc[0][1]); \
  acc[0][2] = fmaf(a.x, b.z, acc[0][2]); acc[0][3] = fmaf(a.x, b.w, acc[0][3]); \
  acc[1][0] = fmaf(a.y, b.x, acc[1][0]); acc[1][1] = fmaf(a.y, b.y, acc[1][1]); \
  acc[1][2] = fmaf(a.y, b.z, acc[1][2]); acc[1][3] = fmaf(a.y, b.w, acc[1][3]); \
  acc[2][0] = fmaf(a.z, b.x, acc[2][0]); acc[2][1] = fmaf(a.z, b.y, acc[2][1]); \
  acc[2][2] = fmaf(a.z, b.z, acc[2][2]); acc[2][3] = fmaf(a.z, b.w, acc[2][3]); \
  acc[3][0] = fmaf(a.w, b.x, acc[3][0]); acc[3][1] = fmaf(a.w, b.y, acc[3][1]); \
  acc[3][2] = fmaf(a.w, b.z, acc[3][2]); acc[3][3] = fmaf(a.w, b.w, acc[3][3]);

// ---------------------------------------------------------------- plain fp32 GEMM (small: wq)
__global__ __launch_bounds__(256) void gemm_f32(const float* __restrict__ A, int lda,
                                                const float* __restrict__ B, int ldb,
                                                float* __restrict__ C, int ldc, int K) {
  __shared__ float As[16][68];
  __shared__ float Bs[16][64];
  const int tid = threadIdx.x;
  const int tx = tid & 15, ty = tid >> 4;
  const int rt = blockIdx.x, ct = blockIdx.y;
  const int arow = tid >> 2, ak0 = (tid & 3) * 4;
  const int bk = tid >> 4, bc0 = (tid & 15) * 4;
  const float* Ap = A + (long)(rt * 64 + arow) * lda + ak0;
  const float* Bp = B + (long)bk * ldb + ct * 64 + bc0;
  float acc[4][4] = {};
  for (int kt = 0; kt < K; kt += 16) {
    float4 a4 = *(const float4*)(Ap + kt);
    float4 b4 = *(const float4*)(Bp + (long)kt * ldb);
    As[ak0 + 0][arow] = a4.x; As[ak0 + 1][arow] = a4.y;
    As[ak0 + 2][arow] = a4.z; As[ak0 + 3][arow] = a4.w;
    *(float4*)&Bs[bk][bc0] = b4;
    __syncthreads();
#pragma unroll
    for (int k = 0; k < 16; ++k) {
      float4 a = *(const float4*)&As[k][ty * 4];
      float4 b = *(const float4*)&Bs[k][tx * 4];
      MICRO_FMA(a, b, acc)
    }
    __syncthreads();
  }
#pragma unroll
  for (int i = 0; i < 4; ++i) {
    float4 o; o.x = acc[i][0]; o.y = acc[i][1]; o.z = acc[i][2]; o.w = acc[i][3];
    *(float4*)(C + (long)(rt * 64 + ty * 4 + i) * ldc + ct * 64 + tx * 4) = o;
  }
}

// ---------------------------------------------------------------- split-K fp32 GEMM, atomic epilogue
// C[M x N] += A[M x K] @ B[K x N] over K-chunk blockIdx.z*KC..+KC. C must be zeroed.
__global__ __launch_bounds__(256) void gemm_f32_splitk(const float* __restrict__ A, int lda,
                                                       const float* __restrict__ B, int ldb,
                                                       float* __restrict__ C, int ldc, int KC) {
  __shared__ float As[16][68];
  __shared__ float Bs[16][64];
  const int tid = threadIdx.x;
  const int tx = tid & 15, ty = tid >> 4;
  const int rt = blockIdx.x, ct = blockIdx.y;
  const int kbase = blockIdx.z * KC;
  const int arow = tid >> 2, ak0 = (tid & 3) * 4;
  const int bk = tid >> 4, bc0 = (tid & 15) * 4;
  const float* Ap = A + (long)(rt * 64 + arow) * lda + ak0;
  const float* Bp = B + (long)bk * ldb + ct * 64 + bc0;
  float acc[4][4] = {};
  for (int kt = kbase; kt < kbase + KC; kt += 16) {
    float4 a4 = *(const float4*)(Ap + kt);
    float4 b4 = *(const float4*)(Bp + (long)kt * ldb);
    As[ak0 + 0][arow] = a4.x; As[ak0 + 1][arow] = a4.y;
    As[ak0 + 2][arow] = a4.z; As[ak0 + 3][arow] = a4.w;
    *(float4*)&Bs[bk][bc0] = b4;
    __syncthreads();
#pragma unroll
    for (int k = 0; k < 16; ++k) {
      float4 a = *(const float4*)&As[k][ty * 4];
      float4 b = *(const float4*)&Bs[k][tx * 4];
      MICRO_FMA(a, b, acc)
    }
    __syncthreads();
  }
#pragma unroll
  for (int i = 0; i < 4; ++i)
#pragma unroll
    for (int j = 0; j < 4; ++j)
      atomicAdd(C + (long)(rt * 64 + ty * 4 + i) * ldc + ct * 64 + tx * 4 + j, acc[i][j]);
}

// ---------------------------------------------------------------- scores + softmax + gumbel
__global__ __launch_bounds__(256) void scores_kernel(const float* __restrict__ uh,
                                                     const float* __restrict__ wq,
                                                     const float* __restrict__ v,
                                                     float* __restrict__ alpha_g,
                                                     float* __restrict__ y_g) {
  const int tid = threadIdx.x;
  const int nt = blockIdx.x;           // n*64 + t
  const int n = nt >> 6;
  __shared__ float uhs[64][65];
  __shared__ float sc[1024];
  __shared__ float psum[4][64];
  __shared__ float red[4];
  const int sl = tid & 63, dq = tid >> 6;

  float wqr[16], vr[16];
#pragma unroll
  for (int j = 0; j < 16; ++j) {
    wqr[j] = wq[nt * 64 + dq * 16 + j];
    vr[j]  = v[dq * 16 + j];
  }
  const float* uhn = uh + (long)n * 65536;

  for (int t = 0; t < 16; ++t) {
#pragma unroll
    for (int i = 0; i < 4; ++i) {
      int fi = (i * 256 + tid) * 4;
      float4 val = *(const float4*)(uhn + t * 4096 + fi);
      int r = fi >> 6, d = fi & 63;
      uhs[r][d] = val.x; uhs[r][d + 1] = val.y; uhs[r][d + 2] = val.z; uhs[r][d + 3] = val.w;
    }
    __syncthreads();
    float acc = 0.f;
#pragma unroll
    for (int j = 0; j < 16; ++j) {
      float x = uhs[sl][dq * 16 + j] + wqr[j];
      acc = fmaf(tanh_fast(x), vr[j], acc);
    }
    psum[dq][sl] = acc;
    __syncthreads();
    if (dq == 0) sc[t * 64 + sl] = psum[0][sl] + psum[1][sl] + psum[2][sl] + psum[3][sl];
    __syncthreads();
  }

  // ---- log_softmax over S=1024 ----
  float lsc[4];
#pragma unroll
  for (int i = 0; i < 4; ++i) lsc[i] = sc[tid + 256 * i];
  const int wv = tid >> 6, ln = tid & 63;

  float m = fmaxf(fmaxf(lsc[0], lsc[1]), fmaxf(lsc[2], lsc[3]));
  m = wredmax(m);
  if (ln == 0) red[wv] = m;
  __syncthreads();
  m = fmaxf(fmaxf(red[0], red[1]), fmaxf(red[2], red[3]));
  __syncthreads();
  float ss = 0.f;
#pragma unroll
  for (int i = 0; i < 4; ++i) ss += __expf(lsc[i] - m);
  ss = wredsum(ss);
  if (ln == 0) red[wv] = ss;
  __syncthreads();
  ss = red[0] + red[1] + red[2] + red[3];
  const float logl = __logf(ss);
  __syncthreads();

  // ---- alpha + gumbel (JAX partitionable threefry, key=(0,42); bits = o0^o1) ----
  float ys[4];
#pragma unroll
  for (int i = 0; i < 4; ++i) {
    int s = tid + 256 * i;
    float la = lsc[i] - m - logl;
    alpha_g[(long)nt * 1024 + s] = __expf(la);
    uint32_t j = (uint32_t)nt * 1024u + (uint32_t)s;
    uint32_t o0, o1;
    threefry_0_42(0u, j, o0, o1);
    uint32_t bits = o0 ^ o1;
    float u = __uint_as_float((bits >> 9) | 0x3f800000u) - 1.0f;
    float g = -__logf(-__logf(u + 1e-20f) + 1e-20f);
    ys[i] = (la + g) * 2.0f;                           // /TEMPERATURE (0.5)
  }

  // ---- softmax over ys ----
  float m2 = fmaxf(fmaxf(ys[0], ys[1]), fmaxf(ys[2], ys[3]));
  m2 = wredmax(m2);
  if (ln == 0) red[wv] = m2;
  __syncthreads();
  m2 = fmaxf(fmaxf(red[0], red[1]), fmaxf(red[2], red[3]));
  __syncthreads();
  float s2 = 0.f;
  float ye[4];
#pragma unroll
  for (int i = 0; i < 4; ++i) { ye[i] = __expf(ys[i] - m2); s2 += ye[i]; }
  s2 = wredsum(s2);
  if (ln == 0) red[wv] = s2;
  __syncthreads();
  s2 = red[0] + red[1] + red[2] + red[3];
  const float rinv = __fdividef(1.f, s2);
#pragma unroll
  for (int i = 0; i < 4; ++i) y_g[(long)nt * 1024 + tid + 256 * i] = ye[i] * rinv;
}

// ---------------------------------------------------------------- context GEMM, split-K, batched
// grid (8, 8, 16): x = vt*4 + kc (variant, K-chunk of 256), y = col tile, z = batch n.
// ctx[(vt*1024 + n*64 + t), :] += P_vt[n] @ mb[n]   (ctx zeroed beforehand)
__global__ __launch_bounds__(256) void gemm_ctx_splitk(const float* __restrict__ alpha,
                                                       const float* __restrict__ yal,
                                                       const float* __restrict__ mb,
                                                       float* __restrict__ ctx) {
  __shared__ float As[16][68];
  __shared__ float Bs[16][64];
  const int tid = threadIdx.x;
  const int tx = tid & 15, ty = tid >> 4;
  const int vt = blockIdx.x >> 2, kc = blockIdx.x & 3;
  const int ct = blockIdx.y, n = blockIdx.z;
  const int kbase = kc * 256;
  const int arow = tid >> 2, ak0 = (tid & 3) * 4;
  const int bk = tid >> 4, bc0 = (tid & 15) * 4;
  const float* Abase = (vt == 0 ? alpha : yal) + (long)n * 65536;
  const float* Ap = Abase + (long)arow * 1024 + ak0;
  const float* Bp = mb + (long)n * 524288 + (long)bk * 512 + ct * 64 + bc0;
  float acc[4][4] = {};
  for (int kt = kbase; kt < kbase + 256; kt += 16) {
    float4 a4 = *(const float4*)(Ap + kt);
    float4 b4 = *(const float4*)(Bp + (long)kt * 512);
    As[ak0 + 0][arow] = a4.x; As[ak0 + 1][arow] = a4.y;
    As[ak0 + 2][arow] = a4.z; As[ak0 + 3][arow] = a4.w;
    *(float4*)&Bs[bk][bc0] = b4;
    __syncthreads();
#pragma unroll
    for (int k = 0; k < 16; ++k) {
      float4 a = *(const float4*)&As[k][ty * 4];
      float4 b = *(const float4*)&Bs[k][tx * 4];
      MICRO_FMA(a, b, acc)
    }
    __syncthreads();
  }
#pragma unroll
  for (int i = 0; i < 4; ++i)
#pragma unroll
    for (int j = 0; j < 4; ++j)
      atomicAdd(ctx + (long)(vt * 1024 + n * 64 + ty * 4 + i) * 512 + ct * 64 + tx * 4 + j,
                acc[i][j]);
}

// ---------------------------------------------------------------- final: out = tanh(preI + ctxP + b)
__global__ __launch_bounds__(256) void out_epilogue(const float* __restrict__ preI,
                                                    const float* __restrict__ ctxP,
                                                    const float* __restrict__ bout,
                                                    float* __restrict__ out) {
  const int i = (blockIdx.x * 256 + threadIdx.x) * 4;   // over 2*1024*512
  const int rem = i & 524287;                           // nt*512 + c
  const int c = i & 511;
  float4 p = *(const float4*)(preI + rem);
  float4 q = *(const float4*)(ctxP + i);
  float4 bb = *(const float4*)(bout + c);
  float4 o;
  o.x = tanh_fast(p.x + q.x + bb.x);
  o.y = tanh_fast(p.y + q.y + bb.y);
  o.z = tanh_fast(p.z + q.z + bb.z);
  o.w = tanh_fast(p.w + q.w + bb.w);
  *(float4*)(out + i) = o;
}

// ---------------------------------------------------------------- launch
// ws layout (14.25 MiB):
//   uh    [0       , 1048576)  floats  (dead after scores -> reused as ctx, re-zeroed)
//   wq    [1048576 , 1114112)
//   yal   [1114112 , 2162688)
//   preI  [2162688 , 2686976)  [1024,512]  input @ W_out[:512]
//   ctxP  [2686976 , 3735552)  [2,1024,512] ctx @ W_out[512:]
// alpha staged in d_out (exactly out_size floats), consumed before overwrite.
extern "C" void kernel_launch(void* const* d_in, const int* in_sizes, int n_in,
                              void* d_out, int out_size, void* d_ws, size_t ws_size,
                              hipStream_t stream) {
  const float* input = (const float*)d_in[0];   // [16,64,512]
  const float* mb    = (const float*)d_in[1];   // [16,1024,512]
  const float* W_q   = (const float*)d_in[2];   // [512,64]
  const float* W_ctx = (const float*)d_in[3];   // [512,64]
  const float* v     = (const float*)d_in[4];   // [64]
  const float* W_out = (const float*)d_in[5];   // [1024,512]
  const float* b_out = (const float*)d_in[6];   // [512]
  float* out = (float*)d_out;                   // [2,16,64,512]
  float* ws = (float*)d_ws;

  float* uh    = ws;
  float* wq    = ws + 1048576;
  float* yal   = ws + 1114112;
  float* preI  = ws + 2162688;
  float* ctxP  = ws + 2686976;
  float* alpha = out;                 // staged in d_out
  float* ctx   = uh;                  // aliases dead uh

  // zero atomic-accumulation targets (graph-capturable async memsets)
  hipMemsetAsync(uh,   0, 1048576 * 4, stream);
  hipMemsetAsync(preI, 0,  524288 * 4, stream);
  hipMemsetAsync(ctxP, 0, 1048576 * 4, stream);

  // uh = mb @ W_ctx   (16384 x 512 @ 512 x 64), split-K x4
  gemm_f32_splitk<<<dim3(256, 1, 4), 256, 0, stream>>>(mb, 512, W_ctx, 64, uh, 64, 128);
  // wq = input @ W_q  (small)
  gemm_f32<<<dim3(16, 1), 256, 0, stream>>>(input, 512, W_q, 64, wq, 64, 512);
  // preI = input @ W_out[:512]  (1024 x 512 @ 512 x 512), split-K x4
  gemm_f32_splitk<<<dim3(16, 8, 4), 256, 0, stream>>>(input, 512, W_out, 512, preI, 512, 128);
  // scores -> alpha (d_out), y_align (ws)
  scores_kernel<<<1024, 256, 0, stream>>>(uh, wq, v, alpha, yal);
  // ctx accumulation target (aliases uh; zero only after scores consumed uh)
  hipMemsetAsync(ctx, 0, 1048576 * 4, stream);
  // ctx[v] = P_v @ mb  (batched, split-K x4)
  gemm_ctx_splitk<<<dim3(8, 8, 16), 256, 0, stream>>>(alpha, yal, mb, ctx);
  // ctxP = ctx @ W_out[512:]  (2048 x 512 @ 512 x 512), split-K x4
  gemm_f32_splitk<<<dim3(32, 8, 4), 256, 0, stream>>>(ctx, 512, W_out + 512 * 512, 512, ctxP, 512, 128);
  // out = tanh(preI + ctxP + b)
  out_epilogue<<<1024, 256, 0, stream>>>(preI, ctxP, b_out, out);
}

// Round 5
// 220.718 us; speedup vs baseline: 1.8985x; 1.8985x over previous
//
#include <hip/hip_runtime.h>
#include <stdint.h>

#define DEV __device__ __forceinline__

typedef __attribute__((ext_vector_type(8))) short short8;   // 8 bf16 (4 VGPRs)
typedef __attribute__((ext_vector_type(4))) float f32x4;    // MFMA acc

// ---------------------------------------------------------------- helpers
DEV float tanh_fast(float x) {
  x = fminf(15.f, fmaxf(-15.f, x));
  float e = __expf(2.f * x);
  return __fdividef(e - 1.f, e + 1.f);
}

DEV unsigned short f2bf(float f) {           // fp32 -> bf16, round-nearest-even
  uint32_t u = __float_as_uint(f);
  u += 0x7FFFu + ((u >> 16) & 1u);
  return (unsigned short)(u >> 16);
}

DEV uint32_t rotl32(uint32_t x, int r) { return (x << r) | (x >> (32 - r)); }

// JAX Threefry-2x32 with key = (0, 42)  (jax.random.key(42))
DEV void threefry_0_42(uint32_t x0, uint32_t x1, uint32_t& o0, uint32_t& o1) {
  const uint32_t ks0 = 0u, ks1 = 42u, ks2 = 0x1BD11BDAu ^ 42u;
  x0 += ks0; x1 += ks1;
#define TFR(r) { x0 += x1; x1 = rotl32(x1, (r)); x1 ^= x0; }
  TFR(13) TFR(15) TFR(26) TFR(6)  x0 += ks1; x1 += ks2 + 1u;
  TFR(17) TFR(29) TFR(16) TFR(24) x0 += ks2; x1 += ks0 + 2u;
  TFR(13) TFR(15) TFR(26) TFR(6)  x0 += ks0; x1 += ks1 + 3u;
  TFR(17) TFR(29) TFR(16) TFR(24) x0 += ks1; x1 += ks2 + 4u;
  TFR(13) TFR(15) TFR(26) TFR(6)  x0 += ks2; x1 += ks0 + 5u;
#undef TFR
  o0 = x0; o1 = x1;
}

DEV float wredmax(float v) {
#pragma unroll
  for (int off = 32; off > 0; off >>= 1) v = fmaxf(v, __shfl_xor(v, off));
  return v;
}
DEV float wredsum(float v) {
#pragma unroll
  for (int off = 32; off > 0; off >>= 1) v += __shfl_xor(v, off);
  return v;
}

// ---------------------------------------------------------------- transpose + cast
// dst[C][R] (bf16) = src[R][C] (fp32)^T. grid (R/64, C/64), 256 threads.
__global__ __launch_bounds__(256) void transpose_cast(const float* __restrict__ src,
                                                      unsigned short* __restrict__ dst,
                                                      int R, int C) {
  __shared__ float tile[64][65];
  const int tid = threadIdx.x;
  const int br = blockIdx.x * 64, bc = blockIdx.y * 64;
  const int lr = tid >> 4, lc4 = (tid & 15) * 4;
#pragma unroll
  for (int i = 0; i < 4; ++i) {
    float4 v = *(const float4*)(src + (long)(br + lr + i * 16) * C + bc + lc4);
    tile[lr + i * 16][lc4 + 0] = v.x;
    tile[lr + i * 16][lc4 + 1] = v.y;
    tile[lr + i * 16][lc4 + 2] = v.z;
    tile[lr + i * 16][lc4 + 3] = v.w;
  }
  __syncthreads();
#pragma unroll
  for (int i = 0; i < 4; ++i) {
    int crow = lr + i * 16;
    ushort4 o;
    o.x = f2bf(tile[lc4 + 0][crow]);
    o.y = f2bf(tile[lc4 + 1][crow]);
    o.z = f2bf(tile[lc4 + 2][crow]);
    o.w = f2bf(tile[lc4 + 3][crow]);
    *(ushort4*)(dst + (long)(bc + crow) * R + br + lc4) = o;
  }
}

// ---------------------------------------------------------------- MFMA GEMM, B^T bf16
// C[M][N] = A_f32[M][K] @ BT_bf16[N][K]^T. Tile 64x64, KT=32, 256 thr = 4 waves,
// each wave a 32x32 quadrant (2x2 of 16x16x32 MFMA). A cast fp32->bf16 on stage.
// If addsrc != null: C[row][col] = acc + addsrc[(row & 1023)][col] (ldadd).
__global__ __launch_bounds__(256) void gemm_bf16t(const float* __restrict__ A, int lda, int K,
                                                  const unsigned short* __restrict__ BT, int ldbt,
                                                  float* __restrict__ C, int ldc,
                                                  const float* __restrict__ addsrc, int ldadd) {
  __shared__ unsigned short As[64][32];
  __shared__ unsigned short Bs[64][32];
  const int tid = threadIdx.x;
  const int mbase = blockIdx.x * 64, nbase = blockIdx.y * 64;
  const int srow = tid >> 2, kseg = (tid & 3) * 8;
  const int wave = tid >> 6, lane = tid & 63;
  const int wm = (wave >> 1) * 32, wn = (wave & 1) * 32;
  const int q = lane >> 4, r = lane & 15;
  const float* ap = A + (long)(mbase + srow) * lda + kseg;
  const unsigned short* bp = BT + (long)(nbase + srow) * ldbt + kseg;
  f32x4 acc[2][2];
#pragma unroll
  for (int i = 0; i < 2; ++i)
#pragma unroll
    for (int j = 0; j < 2; ++j) acc[i][j] = (f32x4){0.f, 0.f, 0.f, 0.f};

  for (int k0 = 0; k0 < K; k0 += 32) {
    float4 f0 = *(const float4*)(ap + k0);
    float4 f1 = *(const float4*)(ap + k0 + 4);
    uint4 braw = *(const uint4*)(bp + k0);
    ushort4 u0, u1;
    u0.x = f2bf(f0.x); u0.y = f2bf(f0.y); u0.z = f2bf(f0.z); u0.w = f2bf(f0.w);
    u1.x = f2bf(f1.x); u1.y = f2bf(f1.y); u1.z = f2bf(f1.z); u1.w = f2bf(f1.w);
    *(ushort4*)&As[srow][kseg]     = u0;
    *(ushort4*)&As[srow][kseg + 4] = u1;
    *(uint4*)&Bs[srow][kseg] = braw;
    __syncthreads();
    short8 a0 = *(const short8*)&As[wm + r][q * 8];
    short8 a1 = *(const short8*)&As[wm + 16 + r][q * 8];
    short8 b0 = *(const short8*)&Bs[wn + r][q * 8];
    short8 b1 = *(const short8*)&Bs[wn + 16 + r][q * 8];
    acc[0][0] = __builtin_amdgcn_mfma_f32_16x16x32_bf16(a0, b0, acc[0][0], 0, 0, 0);
    acc[0][1] = __builtin_amdgcn_mfma_f32_16x16x32_bf16(a0, b1, acc[0][1], 0, 0, 0);
    acc[1][0] = __builtin_amdgcn_mfma_f32_16x16x32_bf16(a1, b0, acc[1][0], 0, 0, 0);
    acc[1][1] = __builtin_amdgcn_mfma_f32_16x16x32_bf16(a1, b1, acc[1][1], 0, 0, 0);
    __syncthreads();
  }
#pragma unroll
  for (int i2 = 0; i2 < 2; ++i2)
#pragma unroll
    for (int j2 = 0; j2 < 2; ++j2) {
      int gcol = nbase + wn + j2 * 16 + r;
#pragma unroll
      for (int reg = 0; reg < 4; ++reg) {
        int grow = mbase + wm + i2 * 16 + q * 4 + reg;
        float val = acc[i2][j2][reg];
        if (addsrc) val += addsrc[(long)(grow & 1023) * ldadd + gcol];
        C[(long)grow * ldc + gcol] = val;
      }
    }
}

// ---------------------------------------------------------------- MFMA context GEMM
// grid (32, 8): x = vt*16 + n, y = d-tile. ctx[vt*1024+n*64+t][d] = P_vt[n][t][s] @ mb[n][s][d].
// A = alpha/yal fp32 [1024][1024] (cast on stage); B = mb fp32, transposed+cast in LDS.
__global__ __launch_bounds__(256) void gemm_ctx_mfma(const float* __restrict__ alpha,
                                                     const float* __restrict__ yal,
                                                     const float* __restrict__ mb,
                                                     float* __restrict__ ctx) {
  __shared__ unsigned short As[64][32];
  __shared__ unsigned short Bs[64][32];
  const int tid = threadIdx.x;
  const int mg = blockIdx.x;            // vt*16 + n
  const int vt = mg >> 4, n = mg & 15;
  const int dbase = blockIdx.y * 64;
  const int wave = tid >> 6, lane = tid & 63;
  const int wm = (wave >> 1) * 32, wn = (wave & 1) * 32;
  const int q = lane >> 4, r = lane & 15;
  const int arow = tid >> 2, akseg = (tid & 3) * 8;
  const int bsrow = tid >> 3, bdseg = (tid & 7) * 8;
  const float* Abase = (vt == 0 ? alpha : yal) + (long)n * 65536;
  const float* ap = Abase + (long)arow * 1024 + akseg;
  const float* bp = mb + (long)n * 524288 + (long)bsrow * 512 + dbase + bdseg;
  f32x4 acc[2][2];
#pragma unroll
  for (int i = 0; i < 2; ++i)
#pragma unroll
    for (int j = 0; j < 2; ++j) acc[i][j] = (f32x4){0.f, 0.f, 0.f, 0.f};

  for (int k0 = 0; k0 < 1024; k0 += 32) {
    float4 f0 = *(const float4*)(ap + k0);
    float4 f1 = *(const float4*)(ap + k0 + 4);
    float4 g0 = *(const float4*)(bp + (long)k0 * 512);
    float4 g1 = *(const float4*)(bp + (long)k0 * 512 + 4);
    ushort4 u0, u1;
    u0.x = f2bf(f0.x); u0.y = f2bf(f0.y); u0.z = f2bf(f0.z); u0.w = f2bf(f0.w);
    u1.x = f2bf(f1.x); u1.y = f2bf(f1.y); u1.z = f2bf(f1.z); u1.w = f2bf(f1.w);
    *(ushort4*)&As[arow][akseg]     = u0;
    *(ushort4*)&As[arow][akseg + 4] = u1;
    // scatter-transpose mb tile: Bs[d][s]
    Bs[bdseg + 0][bsrow] = f2bf(g0.x);
    Bs[bdseg + 1][bsrow] = f2bf(g0.y);
    Bs[bdseg + 2][bsrow] = f2bf(g0.z);
    Bs[bdseg + 3][bsrow] = f2bf(g0.w);
    Bs[bdseg + 4][bsrow] = f2bf(g1.x);
    Bs[bdseg + 5][bsrow] = f2bf(g1.y);
    Bs[bdseg + 6][bsrow] = f2bf(g1.z);
    Bs[bdseg + 7][bsrow] = f2bf(g1.w);
    __syncthreads();
    short8 a0 = *(const short8*)&As[wm + r][q * 8];
    short8 a1 = *(const short8*)&As[wm + 16 + r][q * 8];
    short8 b0 = *(const short8*)&Bs[wn + r][q * 8];
    short8 b1 = *(const short8*)&Bs[wn + 16 + r][q * 8];
    acc[0][0] = __builtin_amdgcn_mfma_f32_16x16x32_bf16(a0, b0, acc[0][0], 0, 0, 0);
    acc[0][1] = __builtin_amdgcn_mfma_f32_16x16x32_bf16(a0, b1, acc[0][1], 0, 0, 0);
    acc[1][0] = __builtin_amdgcn_mfma_f32_16x16x32_bf16(a1, b0, acc[1][0], 0, 0, 0);
    acc[1][1] = __builtin_amdgcn_mfma_f32_16x16x32_bf16(a1, b1, acc[1][1], 0, 0, 0);
    __syncthreads();
  }
#pragma unroll
  for (int i2 = 0; i2 < 2; ++i2)
#pragma unroll
    for (int j2 = 0; j2 < 2; ++j2) {
      int gcol = dbase + wn + j2 * 16 + r;
#pragma unroll
      for (int reg = 0; reg < 4; ++reg) {
        int trow = wm + i2 * 16 + q * 4 + reg;
        long grow = (long)vt * 1024 + n * 64 + trow;
        ctx[grow * 512 + gcol] = acc[i2][j2][reg];
      }
    }
}

// ---------------------------------------------------------------- scores + softmax + gumbel
__global__ __launch_bounds__(256) void scores_kernel(const float* __restrict__ uh,
                                                     const float* __restrict__ wq,
                                                     const float* __restrict__ v,
                                                     float* __restrict__ alpha_g,
                                                     float* __restrict__ y_g) {
  const int tid = threadIdx.x;
  const int nt = blockIdx.x;           // n*64 + t
  const int n = nt >> 6;
  __shared__ float uhs[64][65];
  __shared__ float sc[1024];
  __shared__ float psum[4][64];
  __shared__ float red[4];
  const int sl = tid & 63, dq = tid >> 6;

  float wqr[16], vr[16];
#pragma unroll
  for (int j = 0; j < 16; ++j) {
    wqr[j] = wq[nt * 64 + dq * 16 + j];
    vr[j]  = v[dq * 16 + j];
  }
  const float* uhn = uh + (long)n * 65536;

  for (int t = 0; t < 16; ++t) {
#pragma unroll
    for (int i = 0; i < 4; ++i) {
      int fi = (i * 256 + tid) * 4;
      float4 val = *(const float4*)(uhn + t * 4096 + fi);
      int r = fi >> 6, d = fi & 63;
      uhs[r][d] = val.x; uhs[r][d + 1] = val.y; uhs[r][d + 2] = val.z; uhs[r][d + 3] = val.w;
    }
    __syncthreads();
    float acc = 0.f;
#pragma unroll
    for (int j = 0; j < 16; ++j) {
      float x = uhs[sl][dq * 16 + j] + wqr[j];
      acc = fmaf(tanh_fast(x), vr[j], acc);
    }
    psum[dq][sl] = acc;
    __syncthreads();
    if (dq == 0) sc[t * 64 + sl] = psum[0][sl] + psum[1][sl] + psum[2][sl] + psum[3][sl];
    __syncthreads();
  }

  // ---- log_softmax over S=1024 ----
  float lsc[4];
#pragma unroll
  for (int i = 0; i < 4; ++i) lsc[i] = sc[tid + 256 * i];
  const int wv = tid >> 6, ln = tid & 63;

  float m = fmaxf(fmaxf(lsc[0], lsc[1]), fmaxf(lsc[2], lsc[3]));
  m = wredmax(m);
  if (ln == 0) red[wv] = m;
  __syncthreads();
  m = fmaxf(fmaxf(red[0], red[1]), fmaxf(red[2], red[3]));
  __syncthreads();
  float ss = 0.f;
#pragma unroll
  for (int i = 0; i < 4; ++i) ss += __expf(lsc[i] - m);
  ss = wredsum(ss);
  if (ln == 0) red[wv] = ss;
  __syncthreads();
  ss = red[0] + red[1] + red[2] + red[3];
  const float logl = __logf(ss);
  __syncthreads();

  // ---- alpha + gumbel (JAX partitionable threefry, key=(0,42); bits = o0^o1) ----
  float ys[4];
#pragma unroll
  for (int i = 0; i < 4; ++i) {
    int s = tid + 256 * i;
    float la = lsc[i] - m - logl;
    alpha_g[(long)nt * 1024 + s] = __expf(la);
    uint32_t j = (uint32_t)nt * 1024u + (uint32_t)s;
    uint32_t o0, o1;
    threefry_0_42(0u, j, o0, o1);
    uint32_t bits = o0 ^ o1;
    float u = __uint_as_float((bits >> 9) | 0x3f800000u) - 1.0f;
    float g = -__logf(-__logf(u + 1e-20f) + 1e-20f);
    ys[i] = (la + g) * 2.0f;                           // /TEMPERATURE (0.5)
  }

  // ---- softmax over ys ----
  float m2 = fmaxf(fmaxf(ys[0], ys[1]), fmaxf(ys[2], ys[3]));
  m2 = wredmax(m2);
  if (ln == 0) red[wv] = m2;
  __syncthreads();
  m2 = fmaxf(fmaxf(red[0], red[1]), fmaxf(red[2], red[3]));
  __syncthreads();
  float s2 = 0.f;
  float ye[4];
#pragma unroll
  for (int i = 0; i < 4; ++i) { ye[i] = __expf(ys[i] - m2); s2 += ye[i]; }
  s2 = wredsum(s2);
  if (ln == 0) red[wv] = s2;
  __syncthreads();
  s2 = red[0] + red[1] + red[2] + red[3];
  const float rinv = __fdividef(1.f, s2);
#pragma unroll
  for (int i = 0; i < 4; ++i) y_g[(long)nt * 1024 + tid + 256 * i] = ye[i] * rinv;
}

// ---------------------------------------------------------------- final: out = tanh(ctxP + b)
__global__ __launch_bounds__(256) void out_epilogue(const float* __restrict__ ctxP,
                                                    const float* __restrict__ bout,
                                                    float* __restrict__ out) {
  const int i = (blockIdx.x * 256 + threadIdx.x) * 4;   // over 2*1024*512
  const int c = i & 511;
  float4 qv = *(const float4*)(ctxP + i);
  float4 bb = *(const float4*)(bout + c);
  float4 o;
  o.x = tanh_fast(qv.x + bb.x);
  o.y = tanh_fast(qv.y + bb.y);
  o.z = tanh_fast(qv.z + bb.z);
  o.w = tanh_fast(qv.w + bb.w);
  *(float4*)(out + i) = o;
}

// ---------------------------------------------------------------- launch
// ws layout (15.4 MiB, floats):
//   uh    [0       , 1048576)   fp32 [16384][64]   (dead after scores -> reused as ctx fp32 [2048][512])
//   wq    [1048576 , 1114112)   fp32 [1024][64]
//   yal   [1114112 , 2162688)   fp32 [1024][1024]
//   preI  [2162688 , 2686976)   fp32 [1024][512]   input @ W_out[:512]
//   ctxP  [2686976 , 3735552)   fp32 [2048][512]   (includes preI via addsrc)
//   WctxT [3735552 , 3751936)   bf16 [64][512]
//   WqT   [3751936 , 3768320)   bf16 [64][512]
//   WoutT [3768320 , 4030464)   bf16 [512][1024]
// alpha staged in d_out (1,048,576 floats), consumed by gemm_ctx before overwrite.
extern "C" void kernel_launch(void* const* d_in, const int* in_sizes, int n_in,
                              void* d_out, int out_size, void* d_ws, size_t ws_size,
                              hipStream_t stream) {
  const float* input = (const float*)d_in[0];   // [16,64,512]
  const float* mb    = (const float*)d_in[1];   // [16,1024,512]
  const float* W_q   = (const float*)d_in[2];   // [512,64]
  const float* W_ctx = (const float*)d_in[3];   // [512,64]
  const float* v     = (const float*)d_in[4];   // [64]
  const float* W_out = (const float*)d_in[5];   // [1024,512]
  const float* b_out = (const float*)d_in[6];   // [512]
  float* out = (float*)d_out;                   // [2,16,64,512]
  float* ws = (float*)d_ws;

  float* uh    = ws;
  float* wq    = ws + 1048576;
  float* yal   = ws + 1114112;
  float* preI  = ws + 2162688;
  float* ctxP  = ws + 2686976;
  unsigned short* WctxT = (unsigned short*)(ws + 3735552);
  unsigned short* WqT   = (unsigned short*)(ws + 3751936);
  unsigned short* WoutT = (unsigned short*)(ws + 3768320);
  float* alpha = out;                 // staged in d_out
  float* ctx   = uh;                  // fp32 [2048][512], aliases dead uh

  // weight transposes to B^T bf16 form
  transpose_cast<<<dim3(8, 1), 256, 0, stream>>>(W_ctx, WctxT, 512, 64);
  transpose_cast<<<dim3(8, 1), 256, 0, stream>>>(W_q, WqT, 512, 64);
  transpose_cast<<<dim3(16, 8), 256, 0, stream>>>(W_out, WoutT, 1024, 512);

  // uh = mb @ W_ctx      (16384 x 512 @ 512 x 64)
  gemm_bf16t<<<dim3(256, 1), 256, 0, stream>>>(mb, 512, 512, WctxT, 512, uh, 64, nullptr, 0);
  // wq = input @ W_q     (1024 x 512 @ 512 x 64)
  gemm_bf16t<<<dim3(16, 1), 256, 0, stream>>>(input, 512, 512, WqT, 512, wq, 64, nullptr, 0);
  // preI = input @ W_out[:512]   (1024 x 512 @ 512 x 512)
  gemm_bf16t<<<dim3(16, 8), 256, 0, stream>>>(input, 512, 512, WoutT, 1024, preI, 512, nullptr, 0);
  // scores -> alpha (d_out), y_align (ws)
  scores_kernel<<<1024, 256, 0, stream>>>(uh, wq, v, alpha, yal);
  // ctx[vt,n] = P_vt[n] @ mb[n]  (batched; overwrites dead uh)
  gemm_ctx_mfma<<<dim3(32, 8), 256, 0, stream>>>(alpha, yal, mb, ctx);
  // ctxP = ctx @ W_out[512:] + preI   (2048 x 512 @ 512 x 512)
  gemm_bf16t<<<dim3(32, 8), 256, 0, stream>>>(ctx, 512, 512, WoutT + 512, 1024, ctxP, 512, preI, 512);
  // out = tanh(ctxP + b)
  out_epilogue<<<1024, 256, 0, stream>>>(ctxP, b_out, out);
}

// Round 6
// 188.758 us; speedup vs baseline: 2.2199x; 1.1693x over previous
//
#include <hip/hip_runtime.h>
#include <hip/hip_bf16.h>
#include <stdint.h>

#define DEV __device__ __forceinline__

typedef __attribute__((ext_vector_type(8))) short short8;   // 8 bf16 (4 VGPRs)
typedef __attribute__((ext_vector_type(4))) float f32x4;    // MFMA acc

// ---------------------------------------------------------------- helpers
DEV unsigned short f2bf(float f) {           // fp32 -> bf16, RNE
  uint32_t u = __float_as_uint(f);
  u += 0x7FFFu + ((u >> 16) & 1u);
  return (unsigned short)(u >> 16);
}

DEV uint2 pk4(float4 f) {                    // 4 fp32 -> 4 bf16 (packed cvt)
  union { __hip_bfloat162 h; unsigned u; } a, b;
  a.h = __float22bfloat162_rn(make_float2(f.x, f.y));
  b.h = __float22bfloat162_rn(make_float2(f.z, f.w));
  return make_uint2(a.u, b.u);
}

DEV short8 mk8(uint2 lo, uint2 hi) {
  union { short8 s; uint4 u; } t;
  t.u = make_uint4(lo.x, lo.y, hi.x, hi.y);
  return t.s;
}

DEV uint32_t rotl32(uint32_t x, int r) { return (x << r) | (x >> (32 - r)); }

// JAX Threefry-2x32 with key = (0, 42)  (jax.random.key(42))
DEV void threefry_0_42(uint32_t x0, uint32_t x1, uint32_t& o0, uint32_t& o1) {
  const uint32_t ks0 = 0u, ks1 = 42u, ks2 = 0x1BD11BDAu ^ 42u;
  x0 += ks0; x1 += ks1;
#define TFR(r) { x0 += x1; x1 = rotl32(x1, (r)); x1 ^= x0; }
  TFR(13) TFR(15) TFR(26) TFR(6)  x0 += ks1; x1 += ks2 + 1u;
  TFR(17) TFR(29) TFR(16) TFR(24) x0 += ks2; x1 += ks0 + 2u;
  TFR(13) TFR(15) TFR(26) TFR(6)  x0 += ks0; x1 += ks1 + 3u;
  TFR(17) TFR(29) TFR(16) TFR(24) x0 += ks1; x1 += ks2 + 4u;
  TFR(13) TFR(15) TFR(26) TFR(6)  x0 += ks2; x1 += ks0 + 5u;
#undef TFR
  o0 = x0; o1 = x1;
}

DEV float wredmax(float v) {
#pragma unroll
  for (int off = 32; off > 0; off >>= 1) v = fmaxf(v, __shfl_xor(v, off));
  return v;
}
DEV float wredsum(float v) {
#pragma unroll
  for (int off = 32; off > 0; off >>= 1) v += __shfl_xor(v, off);
  return v;
}

// ---------------------------------------------------------------- transpose + cast
// dst[C][R] (bf16) = src[R][C] (fp32)^T. grid (R/64, C/64), 256 threads.
__global__ __launch_bounds__(256) void transpose_cast(const float* __restrict__ src,
                                                      unsigned short* __restrict__ dst,
                                                      int R, int C) {
  __shared__ float tile[64][65];
  const int tid = threadIdx.x;
  const int br = blockIdx.x * 64, bc = blockIdx.y * 64;
  const int lr = tid >> 4, lc4 = (tid & 15) * 4;
#pragma unroll
  for (int i = 0; i < 4; ++i) {
    float4 v = *(const float4*)(src + (long)(br + lr + i * 16) * C + bc + lc4);
    tile[lr + i * 16][lc4 + 0] = v.x;
    tile[lr + i * 16][lc4 + 1] = v.y;
    tile[lr + i * 16][lc4 + 2] = v.z;
    tile[lr + i * 16][lc4 + 3] = v.w;
  }
  __syncthreads();
#pragma unroll
  for (int i = 0; i < 4; ++i) {
    int crow = lr + i * 16;
    ushort4 o;
    o.x = f2bf(tile[lc4 + 0][crow]);
    o.y = f2bf(tile[lc4 + 1][crow]);
    o.z = f2bf(tile[lc4 + 2][crow]);
    o.w = f2bf(tile[lc4 + 3][crow]);
    *(ushort4*)(dst + (long)(bc + crow) * R + br + lc4) = o;
  }
}

// ---------------------------------------------------------------- MFMA GEMM, B^T bf16
// C[M][N] = scale * (A_f32[M][K] @ BT_bf16[N][K]^T). 64x64 tile, KT=32, 4 waves
// (2x2 of 32x32 quadrants). XOR-swizzled LDS chunks; register prefetch.
__global__ __launch_bounds__(256) void gemm_bf16t(const float* __restrict__ A, int lda, int K,
                                                  const unsigned short* __restrict__ BT, int ldbt,
                                                  float* __restrict__ C, int ldc, float scale) {
  __shared__ unsigned short As[64][32];
  __shared__ unsigned short Bs[64][32];
  const int tid = threadIdx.x;
  const int mbase = blockIdx.x * 64, nbase = blockIdx.y * 64;
  const int srow = tid >> 2, kc = tid & 3;
  const int scol = ((kc ^ (srow & 3)) * 8);            // swizzled 8-elem chunk
  const int wave = tid >> 6, lane = tid & 63;
  const int wm = (wave >> 1) * 32, wn = (wave & 1) * 32;
  const int q = lane >> 4, r = lane & 15;
  const int c0 = ((q ^ (r & 3)) * 8);                  // swizzled frag col
  const float* ap = A + (long)(mbase + srow) * lda + kc * 8;
  const unsigned short* bp = BT + (long)(nbase + srow) * ldbt + kc * 8;
  f32x4 acc[2][2];
#pragma unroll
  for (int i = 0; i < 2; ++i)
#pragma unroll
    for (int j = 0; j < 2; ++j) acc[i][j] = (f32x4){0.f, 0.f, 0.f, 0.f};

  float4 fa0 = *(const float4*)(ap);
  float4 fa1 = *(const float4*)(ap + 4);
  uint4 fb = *(const uint4*)(bp);
  for (int k0 = 0; k0 < K; k0 += 32) {
    uint2 p0 = pk4(fa0), p1 = pk4(fa1);
    *(uint4*)&As[srow][scol] = make_uint4(p0.x, p0.y, p1.x, p1.y);
    *(uint4*)&Bs[srow][scol] = fb;
    __syncthreads();
    if (k0 + 32 < K) {
      fa0 = *(const float4*)(ap + k0 + 32);
      fa1 = *(const float4*)(ap + k0 + 36);
      fb = *(const uint4*)(bp + k0 + 32);
    }
    short8 a0 = *(const short8*)&As[wm + r][c0];
    short8 a1 = *(const short8*)&As[wm + 16 + r][c0];
    short8 b0 = *(const short8*)&Bs[wn + r][c0];
    short8 b1 = *(const short8*)&Bs[wn + 16 + r][c0];
    acc[0][0] = __builtin_amdgcn_mfma_f32_16x16x32_bf16(a0, b0, acc[0][0], 0, 0, 0);
    acc[0][1] = __builtin_amdgcn_mfma_f32_16x16x32_bf16(a0, b1, acc[0][1], 0, 0, 0);
    acc[1][0] = __builtin_amdgcn_mfma_f32_16x16x32_bf16(a1, b0, acc[1][0], 0, 0, 0);
    acc[1][1] = __builtin_amdgcn_mfma_f32_16x16x32_bf16(a1, b1, acc[1][1], 0, 0, 0);
    __syncthreads();
  }
#pragma unroll
  for (int i2 = 0; i2 < 2; ++i2)
#pragma unroll
    for (int j2 = 0; j2 < 2; ++j2) {
      int gcol = nbase + wn + j2 * 16 + r;
#pragma unroll
      for (int reg = 0; reg < 4; ++reg) {
        int grow = mbase + wm + i2 * 16 + q * 4 + reg;
        C[(long)grow * ldc + gcol] = acc[i2][j2][reg] * scale;
      }
    }
}

// ---------------------------------------------------------------- MFMA ctx GEMM, global-B
// grid (32, 16): x = vt*16+n, y -> dbase = y*32. 64(t) x 32(d) tile, K=S=1024.
// A = alpha/yal fp32 (cast on stage); B = mb fp32 read DIRECTLY from global
// (L3-resident), converted in-register. No B LDS -> no transpose conflicts.
__global__ __launch_bounds__(256) void gemm_ctx_mfma(const float* __restrict__ alpha,
                                                     const float* __restrict__ yal,
                                                     const float* __restrict__ mb,
                                                     float* __restrict__ ctx) {
  __shared__ unsigned short As[64][32];
  const int tid = threadIdx.x;
  const int vt = blockIdx.x >> 4, n = blockIdx.x & 15;
  const int dbase = blockIdx.y * 32;
  const int srow = tid >> 2, kc = tid & 3;
  const int scol = ((kc ^ (srow & 3)) * 8);
  const int wave = tid >> 6, lane = tid & 63;
  const int wm = (wave >> 1) * 32, wn = (wave & 1) * 16;
  const int q = lane >> 4, r = lane & 15;
  const int c0 = ((q ^ (r & 3)) * 8);
  const float* Abase = (vt == 0 ? alpha : yal) + (long)n * 65536;
  const float* ap = Abase + (long)srow * 1024 + kc * 8;
  const float* bcol = mb + (long)n * 524288 + dbase + wn + r;  // + s*512
  f32x4 acc[2];
  acc[0] = (f32x4){0.f, 0.f, 0.f, 0.f};
  acc[1] = (f32x4){0.f, 0.f, 0.f, 0.f};

  float4 fa0 = *(const float4*)(ap);
  float4 fa1 = *(const float4*)(ap + 4);
  float bv[8];
#pragma unroll
  for (int j = 0; j < 8; ++j) bv[j] = bcol[(long)(q * 8 + j) * 512];

  for (int k0 = 0; k0 < 1024; k0 += 32) {
    uint2 p0 = pk4(fa0), p1 = pk4(fa1);
    *(uint4*)&As[srow][scol] = make_uint4(p0.x, p0.y, p1.x, p1.y);
    __syncthreads();
    // convert current B frag before prefetch clobbers bv
    float4 blo = make_float4(bv[0], bv[1], bv[2], bv[3]);
    float4 bhi = make_float4(bv[4], bv[5], bv[6], bv[7]);
    short8 b0 = mk8(pk4(blo), pk4(bhi));
    if (k0 + 32 < 1024) {
      fa0 = *(const float4*)(ap + k0 + 32);
      fa1 = *(const float4*)(ap + k0 + 36);
#pragma unroll
      for (int j = 0; j < 8; ++j) bv[j] = bcol[(long)(k0 + 32 + q * 8 + j) * 512];
    }
    short8 a0 = *(const short8*)&As[wm + r][c0];
    short8 a1 = *(const short8*)&As[wm + 16 + r][c0];
    acc[0] = __builtin_amdgcn_mfma_f32_16x16x32_bf16(a0, b0, acc[0], 0, 0, 0);
    acc[1] = __builtin_amdgcn_mfma_f32_16x16x32_bf16(a1, b0, acc[1], 0, 0, 0);
    __syncthreads();
  }
#pragma unroll
  for (int i2 = 0; i2 < 2; ++i2) {
    int gcol = dbase + wn + r;
#pragma unroll
    for (int reg = 0; reg < 4; ++reg) {
      long grow = (long)vt * 1024 + n * 64 + wm + i2 * 16 + q * 4 + reg;
      ctx[grow * 512 + gcol] = acc[i2][reg];
    }
  }
}

// ---------------------------------------------------------------- fused output GEMM
// out[rg][col] = tanh( [input|ctx](rg) @ WoutT^T + b ), rg in [0,2048).
// A row: k<512 -> input[nt][k]; k>=512 -> ctx[v*1024+nt][k-512]. grid (32,8).
__global__ __launch_bounds__(256) void gemm_out_mfma(const float* __restrict__ input,
                                                     const float* __restrict__ ctx,
                                                     const unsigned short* __restrict__ WoutT,
                                                     const float* __restrict__ bout,
                                                     float* __restrict__ out) {
  __shared__ unsigned short As[64][32];
  __shared__ unsigned short Bs[64][32];
  const int tid = threadIdx.x;
  const int mbase = blockIdx.x * 64, nbase = blockIdx.y * 64;
  const int srow = tid >> 2, kc = tid & 3;
  const int scol = ((kc ^ (srow & 3)) * 8);
  const int wave = tid >> 6, lane = tid & 63;
  const int wm = (wave >> 1) * 32, wn = (wave & 1) * 32;
  const int q = lane >> 4, r = lane & 15;
  const int c0 = ((q ^ (r & 3)) * 8);
  const int vv = mbase >> 10, nt = (mbase + srow) & 1023;
  const float* ap_lo = input + (long)nt * 512 + kc * 8;
  const float* ap_hi = ctx + (long)(vv * 1024 + nt) * 512 + kc * 8 - 512;
  const unsigned short* bp = WoutT + (long)(nbase + srow) * 1024 + kc * 8;
  f32x4 acc[2][2];
#pragma unroll
  for (int i = 0; i < 2; ++i)
#pragma unroll
    for (int j = 0; j < 2; ++j) acc[i][j] = (f32x4){0.f, 0.f, 0.f, 0.f};

  float4 fa0 = *(const float4*)(ap_lo);
  float4 fa1 = *(const float4*)(ap_lo + 4);
  uint4 fb = *(const uint4*)(bp);
  for (int k0 = 0; k0 < 1024; k0 += 32) {
    uint2 p0 = pk4(fa0), p1 = pk4(fa1);
    *(uint4*)&As[srow][scol] = make_uint4(p0.x, p0.y, p1.x, p1.y);
    *(uint4*)&Bs[srow][scol] = fb;
    __syncthreads();
    int kn = k0 + 32;
    if (kn < 1024) {
      const float* apn = (kn < 512) ? ap_lo : ap_hi;
      fa0 = *(const float4*)(apn + kn);
      fa1 = *(const float4*)(apn + kn + 4);
      fb = *(const uint4*)(bp + kn);
    }
    short8 a0 = *(const short8*)&As[wm + r][c0];
    short8 a1 = *(const short8*)&As[wm + 16 + r][c0];
    short8 b0 = *(const short8*)&Bs[wn + r][c0];
    short8 b1 = *(const short8*)&Bs[wn + 16 + r][c0];
    acc[0][0] = __builtin_amdgcn_mfma_f32_16x16x32_bf16(a0, b0, acc[0][0], 0, 0, 0);
    acc[0][1] = __builtin_amdgcn_mfma_f32_16x16x32_bf16(a0, b1, acc[0][1], 0, 0, 0);
    acc[1][0] = __builtin_amdgcn_mfma_f32_16x16x32_bf16(a1, b0, acc[1][0], 0, 0, 0);
    acc[1][1] = __builtin_amdgcn_mfma_f32_16x16x32_bf16(a1, b1, acc[1][1], 0, 0, 0);
    __syncthreads();
  }
#pragma unroll
  for (int i2 = 0; i2 < 2; ++i2)
#pragma unroll
    for (int j2 = 0; j2 < 2; ++j2) {
      int gcol = nbase + wn + j2 * 16 + r;
      float bb = bout[gcol];
#pragma unroll
      for (int reg = 0; reg < 4; ++reg) {
        int grow = mbase + wm + i2 * 16 + q * 4 + reg;
        float z = acc[i2][j2][reg] + bb;
        float rc = __fdividef(1.f, 1.f + __expf(2.f * z));  // inf-safe tanh
        out[(long)grow * 512 + gcol] = fmaf(-2.f, rc, 1.f);
      }
    }
}

// ---------------------------------------------------------------- scores + softmax + gumbel
// uh2/wq2 are PRE-SCALED by 2.0 (folded into their GEMM epilogues):
// tanh(wq+uh) = 1 - 2/(1 + exp(uh2+wq2)).
__global__ __launch_bounds__(256) void scores_kernel(const float* __restrict__ uh2,
                                                     const float* __restrict__ wq2,
                                                     const float* __restrict__ v,
                                                     float* __restrict__ alpha_g,
                                                     float* __restrict__ y_g) {
  const int tid = threadIdx.x;
  const int nt = blockIdx.x;           // n*64 + t
  const int n = nt >> 6;
  __shared__ float uhs[64][65];
  __shared__ float sc[1024];
  __shared__ float red[4];
  const int sl = tid >> 2, dq = tid & 3;   // s-lane, d-chunk (intra-quad)

  float wqr[16], vr[16];
#pragma unroll
  for (int c = 0; c < 4; ++c) {
    float4 w = *(const float4*)(wq2 + nt * 64 + dq * 16 + c * 4);
    float4 vv4 = *(const float4*)(v + dq * 16 + c * 4);
    wqr[c*4+0] = w.x; wqr[c*4+1] = w.y; wqr[c*4+2] = w.z; wqr[c*4+3] = w.w;
    vr[c*4+0] = vv4.x; vr[c*4+1] = vv4.y; vr[c*4+2] = vv4.z; vr[c*4+3] = vv4.w;
  }
  float sumv = 0.f;
#pragma unroll
  for (int j = 0; j < 16; ++j) sumv += vr[j];

  const float* uhn = uh2 + (long)n * 65536;
  float4 pre[4];
#pragma unroll
  for (int i = 0; i < 4; ++i) pre[i] = *(const float4*)(uhn + (i * 256 + tid) * 4);

  for (int t = 0; t < 16; ++t) {
#pragma unroll
    for (int i = 0; i < 4; ++i) {
      int fi = (i * 256 + tid) * 4;
      int rr = fi >> 6, d = fi & 63;
      uhs[rr][d]     = pre[i].x; uhs[rr][d + 1] = pre[i].y;
      uhs[rr][d + 2] = pre[i].z; uhs[rr][d + 3] = pre[i].w;
    }
    __syncthreads();
    if (t < 15) {
#pragma unroll
      for (int i = 0; i < 4; ++i)
        pre[i] = *(const float4*)(uhn + (t + 1) * 4096 + (i * 256 + tid) * 4);
    }
    float racc = 0.f;
#pragma unroll
    for (int j = 0; j < 16; ++j) {
      float x2 = uhs[sl][dq * 16 + j] + wqr[j];
      racc += __fdividef(vr[j], 1.f + __expf(x2));
    }
    float part = fmaf(-2.f, racc, sumv);       // sum tanh*v over this 16-chunk
    part += __shfl_xor(part, 1);
    part += __shfl_xor(part, 2);
    if (dq == 0) sc[t * 64 + sl] = part;
    __syncthreads();
  }

  // ---- log_softmax over S=1024 ----
  float lsc[4];
#pragma unroll
  for (int i = 0; i < 4; ++i) lsc[i] = sc[tid + 256 * i];
  const int wv = tid >> 6, ln = tid & 63;

  float m = fmaxf(fmaxf(lsc[0], lsc[1]), fmaxf(lsc[2], lsc[3]));
  m = wredmax(m);
  if (ln == 0) red[wv] = m;
  __syncthreads();
  m = fmaxf(fmaxf(red[0], red[1]), fmaxf(red[2], red[3]));
  __syncthreads();
  float ss = 0.f;
#pragma unroll
  for (int i = 0; i < 4; ++i) ss += __expf(lsc[i] - m);
  ss = wredsum(ss);
  if (ln == 0) red[wv] = ss;
  __syncthreads();
  ss = red[0] + red[1] + red[2] + red[3];
  const float logl = __logf(ss);
  __syncthreads();

  // ---- alpha + gumbel (JAX partitionable threefry, key=(0,42); bits = o0^o1) ----
  float ys[4];
#pragma unroll
  for (int i = 0; i < 4; ++i) {
    int s = tid + 256 * i;
    float la = lsc[i] - m - logl;
    alpha_g[(long)nt * 1024 + s] = __expf(la);
    uint32_t j = (uint32_t)nt * 1024u + (uint32_t)s;
    uint32_t o0, o1;
    threefry_0_42(0u, j, o0, o1);
    uint32_t bits = o0 ^ o1;
    float u = __uint_as_float((bits >> 9) | 0x3f800000u) - 1.0f;
    float g = -__logf(-__logf(u + 1e-20f) + 1e-20f);
    ys[i] = (la + g) * 2.0f;                           // /TEMPERATURE (0.5)
  }

  // ---- softmax over ys ----
  float m2 = fmaxf(fmaxf(ys[0], ys[1]), fmaxf(ys[2], ys[3]));
  m2 = wredmax(m2);
  if (ln == 0) red[wv] = m2;
  __syncthreads();
  m2 = fmaxf(fmaxf(red[0], red[1]), fmaxf(red[2], red[3]));
  __syncthreads();
  float s2 = 0.f;
  float ye[4];
#pragma unroll
  for (int i = 0; i < 4; ++i) { ye[i] = __expf(ys[i] - m2); s2 += ye[i]; }
  s2 = wredsum(s2);
  if (ln == 0) red[wv] = s2;
  __syncthreads();
  s2 = red[0] + red[1] + red[2] + red[3];
  const float rinv = __fdividef(1.f, s2);
#pragma unroll
  for (int i = 0; i < 4; ++i) y_g[(long)nt * 1024 + tid + 256 * i] = ye[i] * rinv;
}

// ---------------------------------------------------------------- launch
// ws layout (9.83 MiB, float units):
//   uh    [0       , 1048576)   fp32 [16384][64], pre-scaled x2 (reused as ctx [2048][512])
//   wq    [1048576 , 1114112)   fp32 [1024][64],  pre-scaled x2
//   yal   [1114112 , 2162688)   fp32 [1024][1024]
//   WctxT [2162688 , 2179072)   bf16 [64][512]
//   WqT   [2179072 , 2195456)   bf16 [64][512]
//   WoutT [2195456 , 2457600)   bf16 [512][1024]
// alpha staged in d_out, consumed by gemm_ctx before gemm_out overwrites it.
extern "C" void kernel_launch(void* const* d_in, const int* in_sizes, int n_in,
                              void* d_out, int out_size, void* d_ws, size_t ws_size,
                              hipStream_t stream) {
  const float* input = (const float*)d_in[0];   // [16,64,512]
  const float* mb    = (const float*)d_in[1];   // [16,1024,512]
  const float* W_q   = (const float*)d_in[2];   // [512,64]
  const float* W_ctx = (const float*)d_in[3];   // [512,64]
  const float* v     = (const float*)d_in[4];   // [64]
  const float* W_out = (const float*)d_in[5];   // [1024,512]
  const float* b_out = (const float*)d_in[6];   // [512]
  float* out = (float*)d_out;                   // [2,16,64,512]
  float* ws = (float*)d_ws;

  float* uh    = ws;
  float* wq    = ws + 1048576;
  float* yal   = ws + 1114112;
  unsigned short* WctxT = (unsigned short*)(ws + 2162688);
  unsigned short* WqT   = (unsigned short*)(ws + 2179072);
  unsigned short* WoutT = (unsigned short*)(ws + 2195456);
  float* alpha = out;                 // staged in d_out
  float* ctx   = uh;                  // fp32 [2048][512], aliases dead uh

  transpose_cast<<<dim3(8, 1), 256, 0, stream>>>(W_ctx, WctxT, 512, 64);
  transpose_cast<<<dim3(8, 1), 256, 0, stream>>>(W_q, WqT, 512, 64);
  transpose_cast<<<dim3(16, 8), 256, 0, stream>>>(W_out, WoutT, 1024, 512);

  // uh = 2*(mb @ W_ctx); wq = 2*(input @ W_q)   (scale folds tanh's 2x)
  gemm_bf16t<<<dim3(256, 1), 256, 0, stream>>>(mb, 512, 512, WctxT, 512, uh, 64, 2.0f);
  gemm_bf16t<<<dim3(16, 1), 256, 0, stream>>>(input, 512, 512, WqT, 512, wq, 64, 2.0f);
  // scores -> alpha (d_out), y_align
  scores_kernel<<<1024, 256, 0, stream>>>(uh, wq, v, alpha, yal);
  // ctx[vt,n] = P_vt[n] @ mb[n]
  gemm_ctx_mfma<<<dim3(32, 16), 256, 0, stream>>>(alpha, yal, mb, ctx);
  // out = tanh([input|ctx] @ W_out + b)
  gemm_out_mfma<<<dim3(32, 8), 256, 0, stream>>>(input, ctx, WoutT, b_out, out);
}

// Round 7
// 177.616 us; speedup vs baseline: 2.3592x; 1.0627x over previous
//
#include <hip/hip_runtime.h>
#include <hip/hip_bf16.h>
#include <stdint.h>

#define DEV __device__ __forceinline__

typedef __attribute__((ext_vector_type(8))) short short8;   // 8 bf16 (4 VGPRs)
typedef __attribute__((ext_vector_type(4))) float f32x4;    // MFMA acc

#define TWO_LOG2E 2.8853900817779268f   // 2*log2(e): exp(2x) == exp2(x*TWO_LOG2E)

// ---------------------------------------------------------------- helpers
DEV unsigned short f2bf(float f) {           // fp32 -> bf16, RNE
  uint32_t u = __float_as_uint(f);
  u += 0x7FFFu + ((u >> 16) & 1u);
  return (unsigned short)(u >> 16);
}

DEV uint2 pk4(float4 f) {                    // 4 fp32 -> 4 bf16 (packed cvt)
  union { __hip_bfloat162 h; unsigned u; } a, b;
  a.h = __float22bfloat162_rn(make_float2(f.x, f.y));
  b.h = __float22bfloat162_rn(make_float2(f.z, f.w));
  return make_uint2(a.u, b.u);
}

DEV short8 mk8(uint2 lo, uint2 hi) {
  union { short8 s; uint4 u; } t;
  t.u = make_uint4(lo.x, lo.y, hi.x, hi.y);
  return t.s;
}

DEV uint32_t rotl32(uint32_t x, int r) { return (x << r) | (x >> (32 - r)); }

// JAX Threefry-2x32 with key = (0, 42)  (jax.random.key(42))
DEV void threefry_0_42(uint32_t x0, uint32_t x1, uint32_t& o0, uint32_t& o1) {
  const uint32_t ks0 = 0u, ks1 = 42u, ks2 = 0x1BD11BDAu ^ 42u;
  x0 += ks0; x1 += ks1;
#define TFR(r) { x0 += x1; x1 = rotl32(x1, (r)); x1 ^= x0; }
  TFR(13) TFR(15) TFR(26) TFR(6)  x0 += ks1; x1 += ks2 + 1u;
  TFR(17) TFR(29) TFR(16) TFR(24) x0 += ks2; x1 += ks0 + 2u;
  TFR(13) TFR(15) TFR(26) TFR(6)  x0 += ks0; x1 += ks1 + 3u;
  TFR(17) TFR(29) TFR(16) TFR(24) x0 += ks1; x1 += ks2 + 4u;
  TFR(13) TFR(15) TFR(26) TFR(6)  x0 += ks2; x1 += ks0 + 5u;
#undef TFR
  o0 = x0; o1 = x1;
}

DEV float wredmax(float v) {
#pragma unroll
  for (int off = 32; off > 0; off >>= 1) v = fmaxf(v, __shfl_xor(v, off));
  return v;
}
DEV float wredsum(float v) {
#pragma unroll
  for (int off = 32; off > 0; off >>= 1) v += __shfl_xor(v, off);
  return v;
}

// ---------------------------------------------------------------- fused transposes (1 dispatch)
// blocks 0..7: W_ctx[512][64] -> WctxT[64][512]; 8..15: W_q; 16..143: W_out[1024][512] -> WoutT[512][1024]
__global__ __launch_bounds__(256) void transpose_all(const float* __restrict__ Wctx,
                                                     const float* __restrict__ Wq,
                                                     const float* __restrict__ Wout,
                                                     unsigned short* __restrict__ WctxT,
                                                     unsigned short* __restrict__ WqT,
                                                     unsigned short* __restrict__ WoutT) {
  __shared__ float tile[64][65];
  const int b = blockIdx.x;
  const float* src; unsigned short* dst; int R, C, br, bc;
  if (b < 8)       { src = Wctx; dst = WctxT; R = 512;  C = 64;  br = b * 64;        bc = 0; }
  else if (b < 16) { src = Wq;   dst = WqT;   R = 512;  C = 64;  br = (b - 8) * 64;  bc = 0; }
  else { int i = b - 16; src = Wout; dst = WoutT; R = 1024; C = 512; br = (i & 15) * 64; bc = (i >> 4) * 64; }
  const int tid = threadIdx.x;
  const int lr = tid >> 4, lc4 = (tid & 15) * 4;
#pragma unroll
  for (int i = 0; i < 4; ++i) {
    float4 v = *(const float4*)(src + (long)(br + lr + i * 16) * C + bc + lc4);
    tile[lr + i * 16][lc4 + 0] = v.x;
    tile[lr + i * 16][lc4 + 1] = v.y;
    tile[lr + i * 16][lc4 + 2] = v.z;
    tile[lr + i * 16][lc4 + 3] = v.w;
  }
  __syncthreads();
#pragma unroll
  for (int i = 0; i < 4; ++i) {
    int crow = lr + i * 16;
    ushort4 o;
    o.x = f2bf(tile[lc4 + 0][crow]);
    o.y = f2bf(tile[lc4 + 1][crow]);
    o.z = f2bf(tile[lc4 + 2][crow]);
    o.w = f2bf(tile[lc4 + 3][crow]);
    *(ushort4*)(dst + (long)(bc + crow) * R + br + lc4) = o;
  }
}

// ---------------------------------------------------------------- merged uh+wq MFMA GEMM
// blocks 0..255: uh[m][0:64] = TWO_LOG2E*(mb @ WctxT^T); 256..271: wq = TWO_LOG2E*(input @ WqT^T).
// K=512, one 64-col tile. 64x64 tile, 4 waves (2x2 of 32x32 quadrants), XOR-swizzled LDS.
__global__ __launch_bounds__(256) void gemm_uhwq(const float* __restrict__ mb,
                                                 const float* __restrict__ input,
                                                 const unsigned short* __restrict__ WctxT,
                                                 const unsigned short* __restrict__ WqT,
                                                 float* __restrict__ uh,
                                                 float* __restrict__ wqo) {
  __shared__ unsigned short As[64][32];
  __shared__ unsigned short Bs[64][32];
  const int tid = threadIdx.x;
  const int bx = blockIdx.x;
  const float* A;  const unsigned short* BT;  float* C;  int mbase;
  if (bx < 256) { A = mb;    BT = WctxT; C = uh;  mbase = bx * 64; }
  else          { A = input; BT = WqT;   C = wqo; mbase = (bx - 256) * 64; }
  const int srow = tid >> 2, kc = tid & 3;
  const int scol = ((kc ^ (srow & 3)) * 8);
  const int wave = tid >> 6, lane = tid & 63;
  const int wm = (wave >> 1) * 32, wn = (wave & 1) * 32;
  const int q = lane >> 4, r = lane & 15;
  const int c0 = ((q ^ (r & 3)) * 8);
  const float* ap = A + (long)(mbase + srow) * 512 + kc * 8;
  const unsigned short* bp = BT + (long)srow * 512 + kc * 8;
  f32x4 acc[2][2];
#pragma unroll
  for (int i = 0; i < 2; ++i)
#pragma unroll
    for (int j = 0; j < 2; ++j) acc[i][j] = (f32x4){0.f, 0.f, 0.f, 0.f};

  float4 fa0 = *(const float4*)(ap);
  float4 fa1 = *(const float4*)(ap + 4);
  uint4 fb = *(const uint4*)(bp);
  for (int k0 = 0; k0 < 512; k0 += 32) {
    uint2 p0 = pk4(fa0), p1 = pk4(fa1);
    *(uint4*)&As[srow][scol] = make_uint4(p0.x, p0.y, p1.x, p1.y);
    *(uint4*)&Bs[srow][scol] = fb;
    __syncthreads();
    if (k0 + 32 < 512) {
      fa0 = *(const float4*)(ap + k0 + 32);
      fa1 = *(const float4*)(ap + k0 + 36);
      fb = *(const uint4*)(bp + k0 + 32);
    }
    short8 a0 = *(const short8*)&As[wm + r][c0];
    short8 a1 = *(const short8*)&As[wm + 16 + r][c0];
    short8 b0 = *(const short8*)&Bs[wn + r][c0];
    short8 b1 = *(const short8*)&Bs[wn + 16 + r][c0];
    acc[0][0] = __builtin_amdgcn_mfma_f32_16x16x32_bf16(a0, b0, acc[0][0], 0, 0, 0);
    acc[0][1] = __builtin_amdgcn_mfma_f32_16x16x32_bf16(a0, b1, acc[0][1], 0, 0, 0);
    acc[1][0] = __builtin_amdgcn_mfma_f32_16x16x32_bf16(a1, b0, acc[1][0], 0, 0, 0);
    acc[1][1] = __builtin_amdgcn_mfma_f32_16x16x32_bf16(a1, b1, acc[1][1], 0, 0, 0);
    __syncthreads();
  }
#pragma unroll
  for (int i2 = 0; i2 < 2; ++i2)
#pragma unroll
    for (int j2 = 0; j2 < 2; ++j2) {
      int gcol = wn + j2 * 16 + r;
#pragma unroll
      for (int reg = 0; reg < 4; ++reg) {
        int grow = mbase + wm + i2 * 16 + q * 4 + reg;
        C[(long)grow * 64 + gcol] = acc[i2][j2][reg] * TWO_LOG2E;
      }
    }
}

// ---------------------------------------------------------------- MFMA ctx GEMM, global-B
__global__ __launch_bounds__(256) void gemm_ctx_mfma(const float* __restrict__ alpha,
                                                     const float* __restrict__ yal,
                                                     const float* __restrict__ mb,
                                                     float* __restrict__ ctx) {
  __shared__ unsigned short As[64][32];
  const int tid = threadIdx.x;
  const int vt = blockIdx.x >> 4, n = blockIdx.x & 15;
  const int dbase = blockIdx.y * 32;
  const int srow = tid >> 2, kc = tid & 3;
  const int scol = ((kc ^ (srow & 3)) * 8);
  const int wave = tid >> 6, lane = tid & 63;
  const int wm = (wave >> 1) * 32, wn = (wave & 1) * 16;
  const int q = lane >> 4, r = lane & 15;
  const int c0 = ((q ^ (r & 3)) * 8);
  const float* Abase = (vt == 0 ? alpha : yal) + (long)n * 65536;
  const float* ap = Abase + (long)srow * 1024 + kc * 8;
  const float* bcol = mb + (long)n * 524288 + dbase + wn + r;  // + s*512
  f32x4 acc[2];
  acc[0] = (f32x4){0.f, 0.f, 0.f, 0.f};
  acc[1] = (f32x4){0.f, 0.f, 0.f, 0.f};

  float4 fa0 = *(const float4*)(ap);
  float4 fa1 = *(const float4*)(ap + 4);
  float bv[8];
#pragma unroll
  for (int j = 0; j < 8; ++j) bv[j] = bcol[(long)(q * 8 + j) * 512];

  for (int k0 = 0; k0 < 1024; k0 += 32) {
    uint2 p0 = pk4(fa0), p1 = pk4(fa1);
    *(uint4*)&As[srow][scol] = make_uint4(p0.x, p0.y, p1.x, p1.y);
    __syncthreads();
    float4 blo = make_float4(bv[0], bv[1], bv[2], bv[3]);
    float4 bhi = make_float4(bv[4], bv[5], bv[6], bv[7]);
    short8 b0 = mk8(pk4(blo), pk4(bhi));
    if (k0 + 32 < 1024) {
      fa0 = *(const float4*)(ap + k0 + 32);
      fa1 = *(const float4*)(ap + k0 + 36);
#pragma unroll
      for (int j = 0; j < 8; ++j) bv[j] = bcol[(long)(k0 + 32 + q * 8 + j) * 512];
    }
    short8 a0 = *(const short8*)&As[wm + r][c0];
    short8 a1 = *(const short8*)&As[wm + 16 + r][c0];
    acc[0] = __builtin_amdgcn_mfma_f32_16x16x32_bf16(a0, b0, acc[0], 0, 0, 0);
    acc[1] = __builtin_amdgcn_mfma_f32_16x16x32_bf16(a1, b0, acc[1], 0, 0, 0);
    __syncthreads();
  }
#pragma unroll
  for (int i2 = 0; i2 < 2; ++i2) {
    int gcol = dbase + wn + r;
#pragma unroll
    for (int reg = 0; reg < 4; ++reg) {
      long grow = (long)vt * 1024 + n * 64 + wm + i2 * 16 + q * 4 + reg;
      ctx[grow * 512 + gcol] = acc[i2][reg];
    }
  }
}

// ---------------------------------------------------------------- fused output GEMM
__global__ __launch_bounds__(256) void gemm_out_mfma(const float* __restrict__ input,
                                                     const float* __restrict__ ctx,
                                                     const unsigned short* __restrict__ WoutT,
                                                     const float* __restrict__ bout,
                                                     float* __restrict__ out) {
  __shared__ unsigned short As[64][32];
  __shared__ unsigned short Bs[64][32];
  const int tid = threadIdx.x;
  const int mbase = blockIdx.x * 64, nbase = blockIdx.y * 64;
  const int srow = tid >> 2, kc = tid & 3;
  const int scol = ((kc ^ (srow & 3)) * 8);
  const int wave = tid >> 6, lane = tid & 63;
  const int wm = (wave >> 1) * 32, wn = (wave & 1) * 32;
  const int q = lane >> 4, r = lane & 15;
  const int c0 = ((q ^ (r & 3)) * 8);
  const int vv = mbase >> 10, nt = (mbase + srow) & 1023;
  const float* ap_lo = input + (long)nt * 512 + kc * 8;
  const float* ap_hi = ctx + (long)(vv * 1024 + nt) * 512 + kc * 8 - 512;
  const unsigned short* bp = WoutT + (long)(nbase + srow) * 1024 + kc * 8;
  f32x4 acc[2][2];
#pragma unroll
  for (int i = 0; i < 2; ++i)
#pragma unroll
    for (int j = 0; j < 2; ++j) acc[i][j] = (f32x4){0.f, 0.f, 0.f, 0.f};

  float4 fa0 = *(const float4*)(ap_lo);
  float4 fa1 = *(const float4*)(ap_lo + 4);
  uint4 fb = *(const uint4*)(bp);
  for (int k0 = 0; k0 < 1024; k0 += 32) {
    uint2 p0 = pk4(fa0), p1 = pk4(fa1);
    *(uint4*)&As[srow][scol] = make_uint4(p0.x, p0.y, p1.x, p1.y);
    *(uint4*)&Bs[srow][scol] = fb;
    __syncthreads();
    int kn = k0 + 32;
    if (kn < 1024) {
      const float* apn = (kn < 512) ? ap_lo : ap_hi;
      fa0 = *(const float4*)(apn + kn);
      fa1 = *(const float4*)(apn + kn + 4);
      fb = *(const uint4*)(bp + kn);
    }
    short8 a0 = *(const short8*)&As[wm + r][c0];
    short8 a1 = *(const short8*)&As[wm + 16 + r][c0];
    short8 b0 = *(const short8*)&Bs[wn + r][c0];
    short8 b1 = *(const short8*)&Bs[wn + 16 + r][c0];
    acc[0][0] = __builtin_amdgcn_mfma_f32_16x16x32_bf16(a0, b0, acc[0][0], 0, 0, 0);
    acc[0][1] = __builtin_amdgcn_mfma_f32_16x16x32_bf16(a0, b1, acc[0][1], 0, 0, 0);
    acc[1][0] = __builtin_amdgcn_mfma_f32_16x16x32_bf16(a1, b0, acc[1][0], 0, 0, 0);
    acc[1][1] = __builtin_amdgcn_mfma_f32_16x16x32_bf16(a1, b1, acc[1][1], 0, 0, 0);
    __syncthreads();
  }
#pragma unroll
  for (int i2 = 0; i2 < 2; ++i2)
#pragma unroll
    for (int j2 = 0; j2 < 2; ++j2) {
      int gcol = nbase + wn + j2 * 16 + r;
      float bb = bout[gcol];
#pragma unroll
      for (int reg = 0; reg < 4; ++reg) {
        int grow = mbase + wm + i2 * 16 + q * 4 + reg;
        float z = acc[i2][j2][reg] + bb;
        float rc = __builtin_amdgcn_rcpf(1.f + __builtin_amdgcn_exp2f(z * TWO_LOG2E));
        out[(long)grow * 512 + gcol] = fmaf(-2.f, rc, 1.f);
      }
    }
}

// ---------------------------------------------------------------- scores + softmax + gumbel (v3)
// No staging LDS. Thread owns s = tid + 256*i (i=0..3): reads uh2 rows directly from
// global (L1/L2-resident), wq2 row + v via LDS broadcast. uh2/wq2 prescaled by
// 2*log2(e): v.tanh(wq+uh) = sumv - 2*sum v[d]*rcp(1 + exp2(uh2+wq2)).
__global__ __launch_bounds__(256) void scores_kernel(const float* __restrict__ uh2,
                                                     const float* __restrict__ wq2,
                                                     const float* __restrict__ v,
                                                     float* __restrict__ alpha_g,
                                                     float* __restrict__ y_g) {
  const int tid = threadIdx.x;
  const int nt = blockIdx.x;           // n*64 + t
  const int n = nt >> 6;
  __shared__ float wvs[64];
  __shared__ float vvs[64];
  __shared__ float red[4];
  if (tid < 64) {
    wvs[tid] = wq2[nt * 64 + tid];
    vvs[tid] = v[tid];
  }
  __syncthreads();

  float sumv = 0.f;
#pragma unroll
  for (int d = 0; d < 64; d += 4) {
    float4 vv = *(const float4*)&vvs[d];
    sumv += vv.x + vv.y + vv.z + vv.w;
  }

  const float* un = uh2 + (long)n * 65536;
  float lsc[4];
#pragma unroll
  for (int i = 0; i < 4; ++i) {
    const float* up = un + (long)(i * 256 + tid) * 64;
    float racc = 0.f;
#pragma unroll
    for (int dc = 0; dc < 16; ++dc) {
      float4 u = *(const float4*)(up + dc * 4);
      float4 w = *(const float4*)&wvs[dc * 4];
      float4 vv = *(const float4*)&vvs[dc * 4];
      racc = fmaf(vv.x, __builtin_amdgcn_rcpf(1.f + __builtin_amdgcn_exp2f(u.x + w.x)), racc);
      racc = fmaf(vv.y, __builtin_amdgcn_rcpf(1.f + __builtin_amdgcn_exp2f(u.y + w.y)), racc);
      racc = fmaf(vv.z, __builtin_amdgcn_rcpf(1.f + __builtin_amdgcn_exp2f(u.z + w.z)), racc);
      racc = fmaf(vv.w, __builtin_amdgcn_rcpf(1.f + __builtin_amdgcn_exp2f(u.w + w.w)), racc);
    }
    lsc[i] = fmaf(-2.f, racc, sumv);   // = sum_d v[d]*tanh(.)
  }

  // ---- log_softmax over S=1024 ----
  const int wv = tid >> 6, ln = tid & 63;
  float m = fmaxf(fmaxf(lsc[0], lsc[1]), fmaxf(lsc[2], lsc[3]));
  m = wredmax(m);
  if (ln == 0) red[wv] = m;
  __syncthreads();
  m = fmaxf(fmaxf(red[0], red[1]), fmaxf(red[2], red[3]));
  __syncthreads();
  float ss = 0.f;
#pragma unroll
  for (int i = 0; i < 4; ++i) ss += __expf(lsc[i] - m);
  ss = wredsum(ss);
  if (ln == 0) red[wv] = ss;
  __syncthreads();
  ss = red[0] + red[1] + red[2] + red[3];
  const float logl = __logf(ss);
  __syncthreads();

  // ---- alpha + gumbel (JAX partitionable threefry, key=(0,42); bits = o0^o1) ----
  float ys[4];
#pragma unroll
  for (int i = 0; i < 4; ++i) {
    int s = tid + 256 * i;
    float la = lsc[i] - m - logl;
    alpha_g[(long)nt * 1024 + s] = __expf(la);
    uint32_t j = (uint32_t)nt * 1024u + (uint32_t)s;
    uint32_t o0, o1;
    threefry_0_42(0u, j, o0, o1);
    uint32_t bits = o0 ^ o1;
    float u = __uint_as_float((bits >> 9) | 0x3f800000u) - 1.0f;
    float g = -__logf(-__logf(u + 1e-20f) + 1e-20f);
    ys[i] = (la + g) * 2.0f;                           // /TEMPERATURE (0.5)
  }

  // ---- softmax over ys ----
  float m2 = fmaxf(fmaxf(ys[0], ys[1]), fmaxf(ys[2], ys[3]));
  m2 = wredmax(m2);
  if (ln == 0) red[wv] = m2;
  __syncthreads();
  m2 = fmaxf(fmaxf(red[0], red[1]), fmaxf(red[2], red[3]));
  __syncthreads();
  float s2 = 0.f;
  float ye[4];
#pragma unroll
  for (int i = 0; i < 4; ++i) { ye[i] = __expf(ys[i] - m2); s2 += ye[i]; }
  s2 = wredsum(s2);
  if (ln == 0) red[wv] = s2;
  __syncthreads();
  s2 = red[0] + red[1] + red[2] + red[3];
  const float rinv = __fdividef(1.f, s2);
#pragma unroll
  for (int i = 0; i < 4; ++i) y_g[(long)nt * 1024 + tid + 256 * i] = ye[i] * rinv;
}

// ---------------------------------------------------------------- launch
// ws layout (9.83 MiB, float units):
//   uh    [0       , 1048576)   fp32 [16384][64], prescaled 2*log2e (reused as ctx [2048][512])
//   wq    [1048576 , 1114112)   fp32 [1024][64],  prescaled 2*log2e
//   yal   [1114112 , 2162688)   fp32 [1024][1024]
//   WctxT [2162688 , 2179072)   bf16 [64][512]
//   WqT   [2179072 , 2195456)   bf16 [64][512]
//   WoutT [2195456 , 2457600)   bf16 [512][1024]
// alpha staged in d_out, consumed by gemm_ctx before gemm_out overwrites it.
extern "C" void kernel_launch(void* const* d_in, const int* in_sizes, int n_in,
                              void* d_out, int out_size, void* d_ws, size_t ws_size,
                              hipStream_t stream) {
  const float* input = (const float*)d_in[0];   // [16,64,512]
  const float* mb    = (const float*)d_in[1];   // [16,1024,512]
  const float* W_q   = (const float*)d_in[2];   // [512,64]
  const float* W_ctx = (const float*)d_in[3];   // [512,64]
  const float* v     = (const float*)d_in[4];   // [64]
  const float* W_out = (const float*)d_in[5];   // [1024,512]
  const float* b_out = (const float*)d_in[6];   // [512]
  float* out = (float*)d_out;                   // [2,16,64,512]
  float* ws = (float*)d_ws;

  float* uh    = ws;
  float* wq    = ws + 1048576;
  float* yal   = ws + 1114112;
  unsigned short* WctxT = (unsigned short*)(ws + 2162688);
  unsigned short* WqT   = (unsigned short*)(ws + 2179072);
  unsigned short* WoutT = (unsigned short*)(ws + 2195456);
  float* alpha = out;                 // staged in d_out
  float* ctx   = uh;                  // fp32 [2048][512], aliases dead uh

  transpose_all<<<144, 256, 0, stream>>>(W_ctx, W_q, W_out, WctxT, WqT, WoutT);
  // uh = 2log2e*(mb @ W_ctx); wq = 2log2e*(input @ W_q)   (one dispatch)
  gemm_uhwq<<<272, 256, 0, stream>>>(mb, input, WctxT, WqT, uh, wq);
  // scores -> alpha (d_out), y_align
  scores_kernel<<<1024, 256, 0, stream>>>(uh, wq, v, alpha, yal);
  // ctx[vt,n] = P_vt[n] @ mb[n]
  gemm_ctx_mfma<<<dim3(32, 16), 256, 0, stream>>>(alpha, yal, mb, ctx);
  // out = tanh([input|ctx] @ W_out + b)
  gemm_out_mfma<<<dim3(32, 8), 256, 0, stream>>>(input, ctx, WoutT, b_out, out);
}

// Round 8
// 153.608 us; speedup vs baseline: 2.7279x; 1.1563x over previous
//
#include <hip/hip_runtime.h>
#include <hip/hip_bf16.h>
#include <stdint.h>

#define DEV __device__ __forceinline__

typedef __attribute__((ext_vector_type(8))) short short8;   // 8 bf16 (4 VGPRs)
typedef __attribute__((ext_vector_type(4))) float f32x4;    // MFMA acc

#define TWO_LOG2E 2.8853900817779268f   // 2*log2(e): exp(2x) == exp2(x*TWO_LOG2E)

// ---------------------------------------------------------------- helpers
DEV unsigned short f2bf(float f) {           // fp32 -> bf16, RNE
  uint32_t u = __float_as_uint(f);
  u += 0x7FFFu + ((u >> 16) & 1u);
  return (unsigned short)(u >> 16);
}

DEV uint2 pk4(float4 f) {                    // 4 fp32 -> 4 bf16 (packed cvt)
  union { __hip_bfloat162 h; unsigned u; } a, b;
  a.h = __float22bfloat162_rn(make_float2(f.x, f.y));
  b.h = __float22bfloat162_rn(make_float2(f.z, f.w));
  return make_uint2(a.u, b.u);
}

DEV short8 mk8(uint2 lo, uint2 hi) {
  union { short8 s; uint4 u; } t;
  t.u = make_uint4(lo.x, lo.y, hi.x, hi.y);
  return t.s;
}

DEV uint32_t rotl32(uint32_t x, int r) { return (x << r) | (x >> (32 - r)); }

// JAX Threefry-2x32 with key = (0, 42)  (jax.random.key(42))
DEV void threefry_0_42(uint32_t x0, uint32_t x1, uint32_t& o0, uint32_t& o1) {
  const uint32_t ks0 = 0u, ks1 = 42u, ks2 = 0x1BD11BDAu ^ 42u;
  x0 += ks0; x1 += ks1;
#define TFR(r) { x0 += x1; x1 = rotl32(x1, (r)); x1 ^= x0; }
  TFR(13) TFR(15) TFR(26) TFR(6)  x0 += ks1; x1 += ks2 + 1u;
  TFR(17) TFR(29) TFR(16) TFR(24) x0 += ks2; x1 += ks0 + 2u;
  TFR(13) TFR(15) TFR(26) TFR(6)  x0 += ks0; x1 += ks1 + 3u;
  TFR(17) TFR(29) TFR(16) TFR(24) x0 += ks1; x1 += ks2 + 4u;
  TFR(13) TFR(15) TFR(26) TFR(6)  x0 += ks2; x1 += ks0 + 5u;
#undef TFR
  o0 = x0; o1 = x1;
}

DEV float wredmax(float v) {
#pragma unroll
  for (int off = 32; off > 0; off >>= 1) v = fmaxf(v, __shfl_xor(v, off));
  return v;
}
DEV float wredsum(float v) {
#pragma unroll
  for (int off = 32; off > 0; off >>= 1) v += __shfl_xor(v, off);
  return v;
}

// ---------------------------------------------------------------- fused transposes (1 dispatch)
__global__ __launch_bounds__(256) void transpose_all(const float* __restrict__ Wctx,
                                                     const float* __restrict__ Wq,
                                                     const float* __restrict__ Wout,
                                                     unsigned short* __restrict__ WctxT,
                                                     unsigned short* __restrict__ WqT,
                                                     unsigned short* __restrict__ WoutT) {
  __shared__ float tile[64][65];
  const int b = blockIdx.x;
  const float* src; unsigned short* dst; int R, C, br, bc;
  if (b < 8)       { src = Wctx; dst = WctxT; R = 512;  C = 64;  br = b * 64;        bc = 0; }
  else if (b < 16) { src = Wq;   dst = WqT;   R = 512;  C = 64;  br = (b - 8) * 64;  bc = 0; }
  else { int i = b - 16; src = Wout; dst = WoutT; R = 1024; C = 512; br = (i & 15) * 64; bc = (i >> 4) * 64; }
  const int tid = threadIdx.x;
  const int lr = tid >> 4, lc4 = (tid & 15) * 4;
#pragma unroll
  for (int i = 0; i < 4; ++i) {
    float4 v = *(const float4*)(src + (long)(br + lr + i * 16) * C + bc + lc4);
    tile[lr + i * 16][lc4 + 0] = v.x;
    tile[lr + i * 16][lc4 + 1] = v.y;
    tile[lr + i * 16][lc4 + 2] = v.z;
    tile[lr + i * 16][lc4 + 3] = v.w;
  }
  __syncthreads();
#pragma unroll
  for (int i = 0; i < 4; ++i) {
    int crow = lr + i * 16;
    ushort4 o;
    o.x = f2bf(tile[lc4 + 0][crow]);
    o.y = f2bf(tile[lc4 + 1][crow]);
    o.z = f2bf(tile[lc4 + 2][crow]);
    o.w = f2bf(tile[lc4 + 3][crow]);
    *(ushort4*)(dst + (long)(bc + crow) * R + br + lc4) = o;
  }
}

// ---------------------------------------------------------------- merged uh+wq MFMA GEMM
// blocks 0..255: uhT[n][d][s] = TWO_LOG2E*(mb @ WctxT^T)  (TRANSPOSED output for scores)
// blocks 256..271: wq[m][d]   = TWO_LOG2E*(input @ WqT^T) (row-major)
__global__ __launch_bounds__(256) void gemm_uhwq(const float* __restrict__ mb,
                                                 const float* __restrict__ input,
                                                 const unsigned short* __restrict__ WctxT,
                                                 const unsigned short* __restrict__ WqT,
                                                 float* __restrict__ uhT,
                                                 float* __restrict__ wqo) {
  __shared__ unsigned short As[64][32];
  __shared__ unsigned short Bs[64][32];
  const int tid = threadIdx.x;
  const int bx = blockIdx.x;
  const float* A;  const unsigned short* BT;  int mbase;
  if (bx < 256) { A = mb;    BT = WctxT; mbase = bx * 64; }
  else          { A = input; BT = WqT;   mbase = (bx - 256) * 64; }
  const int srow = tid >> 2, kc = tid & 3;
  const int scol = ((kc ^ (srow & 3)) * 8);
  const int wave = tid >> 6, lane = tid & 63;
  const int wm = (wave >> 1) * 32, wn = (wave & 1) * 32;
  const int q = lane >> 4, r = lane & 15;
  const int c0 = ((q ^ (r & 3)) * 8);
  const float* ap = A + (long)(mbase + srow) * 512 + kc * 8;
  const unsigned short* bp = BT + (long)srow * 512 + kc * 8;
  f32x4 acc[2][2];
#pragma unroll
  for (int i = 0; i < 2; ++i)
#pragma unroll
    for (int j = 0; j < 2; ++j) acc[i][j] = (f32x4){0.f, 0.f, 0.f, 0.f};

  float4 fa0 = *(const float4*)(ap);
  float4 fa1 = *(const float4*)(ap + 4);
  uint4 fb = *(const uint4*)(bp);
  for (int k0 = 0; k0 < 512; k0 += 32) {
    uint2 p0 = pk4(fa0), p1 = pk4(fa1);
    *(uint4*)&As[srow][scol] = make_uint4(p0.x, p0.y, p1.x, p1.y);
    *(uint4*)&Bs[srow][scol] = fb;
    __syncthreads();
    if (k0 + 32 < 512) {
      fa0 = *(const float4*)(ap + k0 + 32);
      fa1 = *(const float4*)(ap + k0 + 36);
      fb = *(const uint4*)(bp + k0 + 32);
    }
    short8 a0 = *(const short8*)&As[wm + r][c0];
    short8 a1 = *(const short8*)&As[wm + 16 + r][c0];
    short8 b0 = *(const short8*)&Bs[wn + r][c0];
    short8 b1 = *(const short8*)&Bs[wn + 16 + r][c0];
    acc[0][0] = __builtin_amdgcn_mfma_f32_16x16x32_bf16(a0, b0, acc[0][0], 0, 0, 0);
    acc[0][1] = __builtin_amdgcn_mfma_f32_16x16x32_bf16(a0, b1, acc[0][1], 0, 0, 0);
    acc[1][0] = __builtin_amdgcn_mfma_f32_16x16x32_bf16(a1, b0, acc[1][0], 0, 0, 0);
    acc[1][1] = __builtin_amdgcn_mfma_f32_16x16x32_bf16(a1, b1, acc[1][1], 0, 0, 0);
    __syncthreads();
  }
#pragma unroll
  for (int i2 = 0; i2 < 2; ++i2)
#pragma unroll
    for (int j2 = 0; j2 < 2; ++j2) {
      int gcol = wn + j2 * 16 + r;                      // d
      int m = mbase + wm + i2 * 16 + q * 4;             // 4 consecutive rows via reg
      if (bx < 256) {                                   // transposed: uhT[n][d][s]
        int n = m >> 10, s0 = m & 1023;
        float4 o;
        o.x = acc[i2][j2][0] * TWO_LOG2E;
        o.y = acc[i2][j2][1] * TWO_LOG2E;
        o.z = acc[i2][j2][2] * TWO_LOG2E;
        o.w = acc[i2][j2][3] * TWO_LOG2E;
        *(float4*)(uhT + (long)n * 65536 + (long)gcol * 1024 + s0) = o;
      } else {
#pragma unroll
        for (int reg = 0; reg < 4; ++reg)
          wqo[(long)(m + reg) * 64 + gcol] = acc[i2][j2][reg] * TWO_LOG2E;
      }
    }
}

// ---------------------------------------------------------------- MFMA ctx GEMM, global-B
__global__ __launch_bounds__(256) void gemm_ctx_mfma(const float* __restrict__ alpha,
                                                     const float* __restrict__ yal,
                                                     const float* __restrict__ mb,
                                                     float* __restrict__ ctx) {
  __shared__ unsigned short As[64][32];
  const int tid = threadIdx.x;
  const int vt = blockIdx.x >> 4, n = blockIdx.x & 15;
  const int dbase = blockIdx.y * 32;
  const int srow = tid >> 2, kc = tid & 3;
  const int scol = ((kc ^ (srow & 3)) * 8);
  const int wave = tid >> 6, lane = tid & 63;
  const int wm = (wave >> 1) * 32, wn = (wave & 1) * 16;
  const int q = lane >> 4, r = lane & 15;
  const int c0 = ((q ^ (r & 3)) * 8);
  const float* Abase = (vt == 0 ? alpha : yal) + (long)n * 65536;
  const float* ap = Abase + (long)srow * 1024 + kc * 8;
  const float* bcol = mb + (long)n * 524288 + dbase + wn + r;  // + s*512
  f32x4 acc[2];
  acc[0] = (f32x4){0.f, 0.f, 0.f, 0.f};
  acc[1] = (f32x4){0.f, 0.f, 0.f, 0.f};

  float4 fa0 = *(const float4*)(ap);
  float4 fa1 = *(const float4*)(ap + 4);
  float bv[8];
#pragma unroll
  for (int j = 0; j < 8; ++j) bv[j] = bcol[(long)(q * 8 + j) * 512];

  for (int k0 = 0; k0 < 1024; k0 += 32) {
    uint2 p0 = pk4(fa0), p1 = pk4(fa1);
    *(uint4*)&As[srow][scol] = make_uint4(p0.x, p0.y, p1.x, p1.y);
    __syncthreads();
    float4 blo = make_float4(bv[0], bv[1], bv[2], bv[3]);
    float4 bhi = make_float4(bv[4], bv[5], bv[6], bv[7]);
    short8 b0 = mk8(pk4(blo), pk4(bhi));
    if (k0 + 32 < 1024) {
      fa0 = *(const float4*)(ap + k0 + 32);
      fa1 = *(const float4*)(ap + k0 + 36);
#pragma unroll
      for (int j = 0; j < 8; ++j) bv[j] = bcol[(long)(k0 + 32 + q * 8 + j) * 512];
    }
    short8 a0 = *(const short8*)&As[wm + r][c0];
    short8 a1 = *(const short8*)&As[wm + 16 + r][c0];
    acc[0] = __builtin_amdgcn_mfma_f32_16x16x32_bf16(a0, b0, acc[0], 0, 0, 0);
    acc[1] = __builtin_amdgcn_mfma_f32_16x16x32_bf16(a1, b0, acc[1], 0, 0, 0);
    __syncthreads();
  }
#pragma unroll
  for (int i2 = 0; i2 < 2; ++i2) {
    int gcol = dbase + wn + r;
#pragma unroll
    for (int reg = 0; reg < 4; ++reg) {
      long grow = (long)vt * 1024 + n * 64 + wm + i2 * 16 + q * 4 + reg;
      ctx[grow * 512 + gcol] = acc[i2][reg];
    }
  }
}

// ---------------------------------------------------------------- fused output GEMM (64x32 tile)
// grid (32, 16) = 512 blocks (2/CU). out = tanh([input|ctx] @ WoutT^T + b).
__global__ __launch_bounds__(256) void gemm_out_mfma(const float* __restrict__ input,
                                                     const float* __restrict__ ctx,
                                                     const unsigned short* __restrict__ WoutT,
                                                     const float* __restrict__ bout,
                                                     float* __restrict__ out) {
  __shared__ unsigned short As[64][32];
  __shared__ unsigned short Bs[32][32];
  const int tid = threadIdx.x;
  const int mbase = blockIdx.x * 64, nbase = blockIdx.y * 32;
  const int srow = tid >> 2, kc = tid & 3;
  const int scol = ((kc ^ (srow & 3)) * 8);
  const int wave = tid >> 6, lane = tid & 63;
  const int wm = (wave >> 1) * 32, wn = (wave & 1) * 16;
  const int q = lane >> 4, r = lane & 15;
  const int c0 = ((q ^ (r & 3)) * 8);
  const int vv = mbase >> 10, nt = (mbase + srow) & 1023;
  const float* ap_lo = input + (long)nt * 512 + kc * 8;
  const float* ap_hi = ctx + (long)(vv * 1024 + nt) * 512 + kc * 8 - 512;
  const int brow = (tid & 127) >> 2;                  // 0..31 (tid<128 stages B)
  const unsigned short* bp = WoutT + (long)(nbase + brow) * 1024 + kc * 8;
  f32x4 acc[2];
  acc[0] = (f32x4){0.f, 0.f, 0.f, 0.f};
  acc[1] = (f32x4){0.f, 0.f, 0.f, 0.f};

  float4 fa0 = *(const float4*)(ap_lo);
  float4 fa1 = *(const float4*)(ap_lo + 4);
  uint4 fb;
  if (tid < 128) fb = *(const uint4*)(bp);
  for (int k0 = 0; k0 < 1024; k0 += 32) {
    uint2 p0 = pk4(fa0), p1 = pk4(fa1);
    *(uint4*)&As[srow][scol] = make_uint4(p0.x, p0.y, p1.x, p1.y);
    if (tid < 128) *(uint4*)&Bs[brow][(kc ^ (brow & 3)) * 8] = fb;
    __syncthreads();
    int kn = k0 + 32;
    if (kn < 1024) {
      const float* apn = (kn < 512) ? ap_lo : ap_hi;
      fa0 = *(const float4*)(apn + kn);
      fa1 = *(const float4*)(apn + kn + 4);
      if (tid < 128) fb = *(const uint4*)(bp + kn);
    }
    short8 a0 = *(const short8*)&As[wm + r][c0];
    short8 a1 = *(const short8*)&As[wm + 16 + r][c0];
    short8 b0 = *(const short8*)&Bs[wn + r][c0];
    acc[0] = __builtin_amdgcn_mfma_f32_16x16x32_bf16(a0, b0, acc[0], 0, 0, 0);
    acc[1] = __builtin_amdgcn_mfma_f32_16x16x32_bf16(a1, b0, acc[1], 0, 0, 0);
    __syncthreads();
  }
#pragma unroll
  for (int i2 = 0; i2 < 2; ++i2) {
    int gcol = nbase + wn + r;
    float bb = bout[gcol];
#pragma unroll
    for (int reg = 0; reg < 4; ++reg) {
      int grow = mbase + wm + i2 * 16 + q * 4 + reg;
      float z = acc[i2][reg] + bb;
      float rc = __builtin_amdgcn_rcpf(1.f + __builtin_amdgcn_exp2f(z * TWO_LOG2E));
      out[(long)grow * 512 + gcol] = fmaf(-2.f, rc, 1.f);
    }
  }
}

// ---------------------------------------------------------------- scores + softmax + gumbel (v4)
// uhT[n][d][s] layout: thread owns 4 CONSECUTIVE s (s0 = 4*tid) -> every global
// load is wave-contiguous (1 KB/instr). wq2/v via LDS broadcast (conflict-free).
// uhT/wq2 prescaled by 2*log2(e): v.tanh = sumv - 2*sum v[d]*rcp(1+exp2(u+w)).
__global__ __launch_bounds__(256) void scores_kernel(const float* __restrict__ uhT,
                                                     const float* __restrict__ wq2,
                                                     const float* __restrict__ v,
                                                     float* __restrict__ alpha_g,
                                                     float* __restrict__ y_g) {
  const int tid = threadIdx.x;
  const int nt = blockIdx.x;           // n*64 + t
  const int n = nt >> 6;
  __shared__ float wvs[64];
  __shared__ float vvs[64];
  __shared__ float red[4];
  if (tid < 64) {
    wvs[tid] = wq2[nt * 64 + tid];
    vvs[tid] = v[tid];
  }
  __syncthreads();

  float sumv = 0.f;
#pragma unroll
  for (int d = 0; d < 64; d += 4) {
    float4 vv = *(const float4*)&vvs[d];
    sumv += vv.x + vv.y + vv.z + vv.w;
  }

  const float* un = uhT + (long)n * 65536 + tid * 4;   // + d*1024
  float4 racc = make_float4(0.f, 0.f, 0.f, 0.f);
  for (int db = 0; db < 64; db += 8) {
    float4 ub[8];
#pragma unroll
    for (int j = 0; j < 8; ++j) ub[j] = *(const float4*)(un + (long)(db + j) * 1024);
#pragma unroll
    for (int j = 0; j < 8; ++j) {
      float w = wvs[db + j], vvj = vvs[db + j];
      racc.x = fmaf(vvj, __builtin_amdgcn_rcpf(1.f + __builtin_amdgcn_exp2f(ub[j].x + w)), racc.x);
      racc.y = fmaf(vvj, __builtin_amdgcn_rcpf(1.f + __builtin_amdgcn_exp2f(ub[j].y + w)), racc.y);
      racc.z = fmaf(vvj, __builtin_amdgcn_rcpf(1.f + __builtin_amdgcn_exp2f(ub[j].z + w)), racc.z);
      racc.w = fmaf(vvj, __builtin_amdgcn_rcpf(1.f + __builtin_amdgcn_exp2f(ub[j].w + w)), racc.w);
    }
  }
  float lsc[4];
  lsc[0] = fmaf(-2.f, racc.x, sumv);
  lsc[1] = fmaf(-2.f, racc.y, sumv);
  lsc[2] = fmaf(-2.f, racc.z, sumv);
  lsc[3] = fmaf(-2.f, racc.w, sumv);

  // ---- log_softmax over S=1024 ----
  const int wv = tid >> 6, ln = tid & 63;
  float m = fmaxf(fmaxf(lsc[0], lsc[1]), fmaxf(lsc[2], lsc[3]));
  m = wredmax(m);
  if (ln == 0) red[wv] = m;
  __syncthreads();
  m = fmaxf(fmaxf(red[0], red[1]), fmaxf(red[2], red[3]));
  __syncthreads();
  float ss = 0.f;
#pragma unroll
  for (int i = 0; i < 4; ++i) ss += __expf(lsc[i] - m);
  ss = wredsum(ss);
  if (ln == 0) red[wv] = ss;
  __syncthreads();
  ss = red[0] + red[1] + red[2] + red[3];
  const float logl = __logf(ss);
  __syncthreads();

  // ---- alpha + gumbel (JAX partitionable threefry, key=(0,42); bits = o0^o1) ----
  const uint32_t jbase = (uint32_t)nt * 1024u + (uint32_t)tid * 4u;
  float ys[4];
  float4 av;
#pragma unroll
  for (int i = 0; i < 4; ++i) {
    float la = lsc[i] - m - logl;
    ((float*)&av)[i] = __expf(la);
    uint32_t o0, o1;
    threefry_0_42(0u, jbase + i, o0, o1);
    uint32_t bits = o0 ^ o1;
    float u = __uint_as_float((bits >> 9) | 0x3f800000u) - 1.0f;
    float g = -__logf(-__logf(u + 1e-20f) + 1e-20f);
    ys[i] = (la + g) * 2.0f;                           // /TEMPERATURE (0.5)
  }
  *(float4*)(alpha_g + (long)nt * 1024 + tid * 4) = av;

  // ---- softmax over ys ----
  float m2 = fmaxf(fmaxf(ys[0], ys[1]), fmaxf(ys[2], ys[3]));
  m2 = wredmax(m2);
  if (ln == 0) red[wv] = m2;
  __syncthreads();
  m2 = fmaxf(fmaxf(red[0], red[1]), fmaxf(red[2], red[3]));
  __syncthreads();
  float s2 = 0.f;
  float4 ye;
#pragma unroll
  for (int i = 0; i < 4; ++i) { ((float*)&ye)[i] = __expf(ys[i] - m2); s2 += ((float*)&ye)[i]; }
  s2 = wredsum(s2);
  if (ln == 0) red[wv] = s2;
  __syncthreads();
  s2 = red[0] + red[1] + red[2] + red[3];
  const float rinv = __fdividef(1.f, s2);
  ye.x *= rinv; ye.y *= rinv; ye.z *= rinv; ye.w *= rinv;
  *(float4*)(y_g + (long)nt * 1024 + tid * 4) = ye;
}

// ---------------------------------------------------------------- launch
// ws layout (9.83 MiB, float units):
//   uhT   [0       , 1048576)   fp32 [16][64][1024] TRANSPOSED, prescaled (reused as ctx)
//   wq    [1048576 , 1114112)   fp32 [1024][64], prescaled
//   yal   [1114112 , 2162688)   fp32 [1024][1024]
//   WctxT [2162688 , 2179072)   bf16 [64][512]
//   WqT   [2179072 , 2195456)   bf16 [64][512]
//   WoutT [2195456 , 2457600)   bf16 [512][1024]
// alpha staged in d_out, consumed by gemm_ctx before gemm_out overwrites it.
extern "C" void kernel_launch(void* const* d_in, const int* in_sizes, int n_in,
                              void* d_out, int out_size, void* d_ws, size_t ws_size,
                              hipStream_t stream) {
  const float* input = (const float*)d_in[0];   // [16,64,512]
  const float* mb    = (const float*)d_in[1];   // [16,1024,512]
  const float* W_q   = (const float*)d_in[2];   // [512,64]
  const float* W_ctx = (const float*)d_in[3];   // [512,64]
  const float* v     = (const float*)d_in[4];   // [64]
  const float* W_out = (const float*)d_in[5];   // [1024,512]
  const float* b_out = (const float*)d_in[6];   // [512]
  float* out = (float*)d_out;                   // [2,16,64,512]
  float* ws = (float*)d_ws;

  float* uhT   = ws;
  float* wq    = ws + 1048576;
  float* yal   = ws + 1114112;
  unsigned short* WctxT = (unsigned short*)(ws + 2162688);
  unsigned short* WqT   = (unsigned short*)(ws + 2179072);
  unsigned short* WoutT = (unsigned short*)(ws + 2195456);
  float* alpha = out;                 // staged in d_out
  float* ctx   = uhT;                 // fp32 [2048][512], aliases dead uhT

  transpose_all<<<144, 256, 0, stream>>>(W_ctx, W_q, W_out, WctxT, WqT, WoutT);
  gemm_uhwq<<<272, 256, 0, stream>>>(mb, input, WctxT, WqT, uhT, wq);
  scores_kernel<<<1024, 256, 0, stream>>>(uhT, wq, v, alpha, yal);
  gemm_ctx_mfma<<<dim3(32, 16), 256, 0, stream>>>(alpha, yal, mb, ctx);
  gemm_out_mfma<<<dim3(32, 16), 256, 0, stream>>>(input, ctx, WoutT, b_out, out);
}